// Round 1
// baseline (1436.055 us; speedup 1.0000x reference)
//
#include <hip/hip_runtime.h>
#include <math.h>

#define NN 100000
#define EE 1600000
#define ET 1700000   // EE + NN self loops
#define NEG 0.2f
#define NCH 98       // ceil(NN/1024)

// ---------------- ws layout (bytes) ----------------
static constexpr size_t OFF_H1   = 0;                                  // N*64 f32
static constexpr size_t OFF_HELU = OFF_H1   + (size_t)NN*64*4;         // N*64 f32
static constexpr size_t OFF_AS1  = OFF_HELU + (size_t)NN*64*4;         // N*8
static constexpr size_t OFF_AD1  = OFF_AS1  + (size_t)NN*8*4;
static constexpr size_t OFF_AS2  = OFF_AD1  + (size_t)NN*8*4;
static constexpr size_t OFF_AD2  = OFF_AS2  + (size_t)NN*8*4;
static constexpr size_t OFF_WS2  = OFF_AD2  + (size_t)NN*8*4;          // 512 f32
static constexpr size_t OFF_WD2  = OFF_WS2  + 512*4;
static constexpr size_t OFF_HIST = OFF_WD2  + 512*4;                   // N int
static constexpr size_t OFF_INC  = OFF_HIST + (size_t)NN*4;            // N int
static constexpr size_t OFF_PART = OFF_INC  + (size_t)NN*4;            // 128 int
static constexpr size_t OFF_OFFS = OFF_PART + 128*4;                   // 128 int
static constexpr size_t OFF_RP   = OFF_OFFS + 128*4;                   // N+1 int
static constexpr size_t OFF_CUR  = OFF_RP   + (size_t)(NN+1)*4;        // N int
static constexpr size_t OFF_SRC  = OFF_CUR  + (size_t)NN*4;           // ET int
static constexpr size_t OFF_AGG  = ((OFF_SRC + (size_t)ET*4 + 255) & ~(size_t)255); // N*512 f32

// ---------------- GEMM1: h1 = x[N,256] @ W1[256,64] ----------------
__global__ __launch_bounds__(256) void k_gemm1(const float* __restrict__ x,
                                               const float* __restrict__ W1,
                                               float* __restrict__ h1) {
  __shared__ float xs[128 * 68];
  __shared__ float wsh[64 * 64];
  const int t = threadIdx.x;
  const int lane = t & 63;
  const int wv = t >> 6;
  const int row0 = blockIdx.x * 128;
  float acc[32];
#pragma unroll
  for (int i = 0; i < 32; i++) acc[i] = 0.f;
  for (int kt = 0; kt < 4; kt++) {
#pragma unroll
    for (int i = 0; i < 8; i++) {           // stage x tile 128x64
      int s = i * 256 + t;
      int row = s >> 4, c4 = s & 15;
      float4 v = make_float4(0.f, 0.f, 0.f, 0.f);
      if (row0 + row < NN) v = ((const float4*)x)[(size_t)(row0 + row) * 64 + kt * 16 + c4];
      *((float4*)&xs[row * 68 + c4 * 4]) = v;
    }
#pragma unroll
    for (int i = 0; i < 4; i++) {           // stage W1 tile 64x64
      int s = i * 256 + t;
      int k = s >> 4, c4 = s & 15;
      float4 v = ((const float4*)W1)[(kt * 64 + k) * 16 + c4];
      *((float4*)&wsh[k * 64 + c4 * 4]) = v;
    }
    __syncthreads();
    for (int k4 = 0; k4 < 16; k4++) {
      float w0 = wsh[(k4 * 4 + 0) * 64 + lane];
      float w1 = wsh[(k4 * 4 + 1) * 64 + lane];
      float w2 = wsh[(k4 * 4 + 2) * 64 + lane];
      float w3 = wsh[(k4 * 4 + 3) * 64 + lane];
#pragma unroll
      for (int i = 0; i < 32; i++) {
        float4 xv = *((const float4*)&xs[(wv * 32 + i) * 68 + k4 * 4]);
        acc[i] += xv.x * w0 + xv.y * w1 + xv.z * w2 + xv.w * w3;
      }
    }
    __syncthreads();
  }
#pragma unroll
  for (int i = 0; i < 32; i++) {
    int row = row0 + wv * 32 + i;
    if (row < NN) h1[(size_t)row * 64 + lane] = acc[i];
  }
}

// ---------------- layer-1 attention logits per node ----------------
__global__ void k_alpha1(const float* __restrict__ h1, const float* __restrict__ a_src1,
                         const float* __restrict__ a_dst1, float* __restrict__ as1,
                         float* __restrict__ ad1) {
  int g = blockIdx.x * 256 + threadIdx.x;
  if (g >= NN * 8) return;
  int n = g >> 3, h = g & 7;
  float s = 0.f, d = 0.f;
#pragma unroll
  for (int f = 0; f < 8; f++) {
    float v = h1[(size_t)n * 64 + h * 8 + f];
    s += v * a_src1[h * 8 + f];
    d += v * a_dst1[h * 8 + f];
  }
  as1[g] = s;
  ad1[g] = d;
}

// ---------------- project a_src2/a_dst2 through W2: [64,8] each ----------------
__global__ void k_w2proj(const float* __restrict__ W2, const float* __restrict__ a_src2,
                         const float* __restrict__ a_dst2, float* __restrict__ ws2,
                         float* __restrict__ wd2) {
  int t = threadIdx.x;  // 512 threads: t = k*8+h
  int k = t >> 3, h = t & 7;
  float s = 0.f, d = 0.f;
  for (int f = 0; f < 64; f++) {
    float w = W2[k * 512 + h * 64 + f];
    s += w * a_src2[h * 64 + f];
    d += w * a_dst2[h * 64 + f];
  }
  ws2[t] = s;
  wd2[t] = d;
}

// ---------------- counting sort by dst ----------------
__global__ void k_hist(const int* __restrict__ edge, int* __restrict__ hist) {
  int e = blockIdx.x * 256 + threadIdx.x;
  if (e >= ET) return;
  int d = (e < EE) ? edge[EE + e] : (e - EE);
  atomicAdd(&hist[d], 1);
}

__global__ void k_scan_a(const int* __restrict__ hist, int* __restrict__ inc,
                         int* __restrict__ part) {
  __shared__ int sm[1024];
  int t = threadIdx.x, c = blockIdx.x;
  int i = c * 1024 + t;
  int v = (i < NN) ? hist[i] : 0;
  sm[t] = v;
  for (int off = 1; off < 1024; off <<= 1) {
    __syncthreads();
    int a = (t >= off) ? sm[t - off] : 0;
    __syncthreads();
    sm[t] += a;
  }
  if (i < NN) inc[i] = sm[t];
  if (t == 1023) part[c] = sm[1023];
}

__global__ void k_scan_b(const int* __restrict__ part, int* __restrict__ offs) {
  if (threadIdx.x == 0 && blockIdx.x == 0) {
    int run = 0;
    for (int c = 0; c < NCH; c++) {
      offs[c] = run;
      run += part[c];
    }
  }
}

__global__ void k_scan_c(const int* __restrict__ hist, const int* __restrict__ inc,
                         const int* __restrict__ offs, int* __restrict__ rp,
                         int* __restrict__ cur) {
  int t = threadIdx.x, c = blockIdx.x;
  int i = c * 1024 + t;
  if (i < NN) {
    int r = inc[i] - hist[i] + offs[c];
    rp[i] = r;
    cur[i] = r;
  }
  if (i == 0) rp[NN] = ET;
}

__global__ void k_scatter(const int* __restrict__ edge, int* __restrict__ cur,
                          int* __restrict__ ssrc) {
  int e = blockIdx.x * 256 + threadIdx.x;
  if (e >= ET) return;
  int s, d;
  if (e < EE) { s = edge[e]; d = edge[EE + e]; } else { s = e - EE; d = s; }
  int pos = atomicAdd(&cur[d], 1);
  ssrc[pos] = s;
}

// ---------------- layer-1 aggregation: online softmax, wave per dst ----------------
__global__ __launch_bounds__(256) void k_agg1(
    const float* __restrict__ h1, const float* __restrict__ as1,
    const float* __restrict__ ad1, const float* __restrict__ b1,
    const int* __restrict__ rp, const int* __restrict__ ssrc,
    const float* __restrict__ ws2, const float* __restrict__ wd2,
    float* __restrict__ helu, float* __restrict__ as2, float* __restrict__ ad2) {
  int lane = threadIdx.x & 63;
  int d = blockIdx.x * 4 + (threadIdx.x >> 6);
  if (d >= NN) return;
  int hl = lane >> 3;  // lane's head (concat layout: lane = h*8+f)
  float adv = ad1[d * 8 + hl];
  int r0 = rp[d], r1 = rp[d + 1];
  float m = -1e30f, l = 0.f, acc = 0.f;
  for (int idx = r0; idx < r1; idx++) {
    int s = ssrc[idx];
    float ev = as1[s * 8 + hl] + adv;
    ev = ev > 0.f ? ev : NEG * ev;
    float nm = fmaxf(m, ev);
    float sc = __expf(m - nm);
    float p = __expf(ev - nm);
    float g = h1[(size_t)s * 64 + lane];
    l = l * sc + p;
    acc = acc * sc + p * g;
    m = nm;
  }
  float val = acc / l + b1[lane];
  val = val > 0.f ? val : __expf(val) - 1.f;  // ELU
  helu[(size_t)d * 64 + lane] = val;
  // layer-2 logits: as2[d,h] = sum_k helu[d,k]*ws2[k,h]
#pragma unroll
  for (int h = 0; h < 8; h++) {
    float ps = val * ws2[lane * 8 + h];
    float pd = val * wd2[lane * 8 + h];
#pragma unroll
    for (int off = 32; off; off >>= 1) {
      ps += __shfl_xor(ps, off, 64);
      pd += __shfl_xor(pd, off, 64);
    }
    if (lane == 0) {
      as2[d * 8 + h] = ps;
      ad2[d * 8 + h] = pd;
    }
  }
}

// ---------------- layer-2 aggregation in 64-dim space (deferred matmul) ----------------
__global__ __launch_bounds__(256) void k_agg2(
    const float* __restrict__ helu, const float* __restrict__ as2,
    const float* __restrict__ ad2, const int* __restrict__ rp,
    const int* __restrict__ ssrc, float* __restrict__ agg) {
  int lane = threadIdx.x & 63;
  int d = blockIdx.x * 4 + (threadIdx.x >> 6);
  if (d >= NN) return;
  float ad[8], m[8], l[8], acc[8];
#pragma unroll
  for (int h = 0; h < 8; h++) {
    ad[h] = ad2[d * 8 + h];
    m[h] = -1e30f;
    l[h] = 0.f;
    acc[h] = 0.f;
  }
  int r0 = rp[d], r1 = rp[d + 1];
  for (int idx = r0; idx < r1; idx++) {
    int s = ssrc[idx];
    float g = helu[(size_t)s * 64 + lane];
#pragma unroll
    for (int h = 0; h < 8; h++) {
      float ev = as2[s * 8 + h] + ad[h];
      ev = ev > 0.f ? ev : NEG * ev;
      float nm = fmaxf(m[h], ev);
      float sc = __expf(m[h] - nm);
      float p = __expf(ev - nm);
      l[h] = l[h] * sc + p;
      acc[h] = acc[h] * sc + p * g;
      m[h] = nm;
    }
  }
#pragma unroll
  for (int h = 0; h < 8; h++) agg[(size_t)d * 512 + h * 64 + lane] = acc[h] / l[h];
}

// ---------------- GEMM2: out = (1/8)*agg[N,512] @ W2'[512,64] + b2 ----------------
// W2'[h*64+kk][f] = W2[kk][h*64+f]; with 64-aligned K-tiles, h == kt.
__global__ __launch_bounds__(256) void k_gemm2(const float* __restrict__ agg,
                                               const float* __restrict__ W2,
                                               const float* __restrict__ b2,
                                               float* __restrict__ out) {
  __shared__ float xs[128 * 68];
  __shared__ float wsh[64 * 64];
  const int t = threadIdx.x;
  const int lane = t & 63;
  const int wv = t >> 6;
  const int row0 = blockIdx.x * 128;
  float acc[32];
#pragma unroll
  for (int i = 0; i < 32; i++) acc[i] = 0.f;
  for (int kt = 0; kt < 8; kt++) {
#pragma unroll
    for (int i = 0; i < 8; i++) {  // stage agg tile 128x64
      int s = i * 256 + t;
      int row = s >> 4, c4 = s & 15;
      float4 v = make_float4(0.f, 0.f, 0.f, 0.f);
      if (row0 + row < NN) v = ((const float4*)agg)[(size_t)(row0 + row) * 128 + kt * 16 + c4];
      *((float4*)&xs[row * 68 + c4 * 4]) = v;
    }
#pragma unroll
    for (int i = 0; i < 4; i++) {  // stage W2 block (h=kt): [kk=0..63][f=0..63]
      int s = i * 256 + t;
      int k = s >> 4, c4 = s & 15;
      float4 v = ((const float4*)W2)[(size_t)k * 128 + kt * 16 + c4];
      *((float4*)&wsh[k * 64 + c4 * 4]) = v;
    }
    __syncthreads();
    for (int k4 = 0; k4 < 16; k4++) {
      float w0 = wsh[(k4 * 4 + 0) * 64 + lane];
      float w1 = wsh[(k4 * 4 + 1) * 64 + lane];
      float w2 = wsh[(k4 * 4 + 2) * 64 + lane];
      float w3 = wsh[(k4 * 4 + 3) * 64 + lane];
#pragma unroll
      for (int i = 0; i < 32; i++) {
        float4 xv = *((const float4*)&xs[(wv * 32 + i) * 68 + k4 * 4]);
        acc[i] += xv.x * w0 + xv.y * w1 + xv.z * w2 + xv.w * w3;
      }
    }
    __syncthreads();
  }
  float bb = b2[lane];
#pragma unroll
  for (int i = 0; i < 32; i++) {
    int row = row0 + wv * 32 + i;
    if (row < NN) out[(size_t)row * 64 + lane] = 0.125f * acc[i] + bb;
  }
}

extern "C" void kernel_launch(void* const* d_in, const int* in_sizes, int n_in,
                              void* d_out, int out_size, void* d_ws, size_t ws_size,
                              hipStream_t stream) {
  const float* x      = (const float*)d_in[0];
  const float* W1     = (const float*)d_in[1];
  const float* a_src1 = (const float*)d_in[2];
  const float* a_dst1 = (const float*)d_in[3];
  const float* b1     = (const float*)d_in[4];
  const float* W2     = (const float*)d_in[5];
  const float* a_src2 = (const float*)d_in[6];
  const float* a_dst2 = (const float*)d_in[7];
  const float* b2     = (const float*)d_in[8];
  const int*   edge   = (const int*)d_in[9];

  char* ws = (char*)d_ws;
  float* h1   = (float*)(ws + OFF_H1);
  float* helu = (float*)(ws + OFF_HELU);
  float* as1  = (float*)(ws + OFF_AS1);
  float* ad1  = (float*)(ws + OFF_AD1);
  float* as2  = (float*)(ws + OFF_AS2);
  float* ad2  = (float*)(ws + OFF_AD2);
  float* ws2  = (float*)(ws + OFF_WS2);
  float* wd2  = (float*)(ws + OFF_WD2);
  int* hist   = (int*)(ws + OFF_HIST);
  int* inc    = (int*)(ws + OFF_INC);
  int* part   = (int*)(ws + OFF_PART);
  int* offs   = (int*)(ws + OFF_OFFS);
  int* rp     = (int*)(ws + OFF_RP);
  int* cur    = (int*)(ws + OFF_CUR);
  int* ssrc   = (int*)(ws + OFF_SRC);
  float* agg  = (float*)(ws + OFF_AGG);
  float* out  = (float*)d_out;

  hipMemsetAsync(hist, 0, (size_t)NN * 4, stream);

  k_gemm1<<<(NN + 127) / 128, 256, 0, stream>>>(x, W1, h1);
  k_alpha1<<<(NN * 8 + 255) / 256, 256, 0, stream>>>(h1, a_src1, a_dst1, as1, ad1);
  k_w2proj<<<1, 512, 0, stream>>>(W2, a_src2, a_dst2, ws2, wd2);
  k_hist<<<(ET + 255) / 256, 256, 0, stream>>>(edge, hist);
  k_scan_a<<<NCH, 1024, 0, stream>>>(hist, inc, part);
  k_scan_b<<<1, 64, 0, stream>>>(part, offs);
  k_scan_c<<<NCH, 1024, 0, stream>>>(hist, inc, offs, rp, cur);
  k_scatter<<<(ET + 255) / 256, 256, 0, stream>>>(edge, cur, ssrc);
  k_agg1<<<NN / 4, 256, 0, stream>>>(h1, as1, ad1, b1, rp, ssrc, ws2, wd2, helu, as2, ad2);
  k_agg2<<<NN / 4, 256, 0, stream>>>(helu, as2, ad2, rp, ssrc, agg);
  k_gemm2<<<(NN + 127) / 128, 256, 0, stream>>>(agg, W2, b2, out);
}

// Round 2
// 1148.871 us; speedup vs baseline: 1.2500x; 1.2500x over previous
//
#include <hip/hip_runtime.h>
#include <math.h>

#define NN 100000
#define EE 1600000
#define ET 1700000   // EE + NN self loops
#define NEG 0.2f
#define NCH 98       // ceil(NN/1024)

// ---------------- ws layout (bytes) ----------------
static constexpr size_t OFF_H1   = 0;                                  // N*64 f32
static constexpr size_t OFF_HELU = OFF_H1   + (size_t)NN*64*4;         // N*64 f32
static constexpr size_t OFF_AS1  = OFF_HELU + (size_t)NN*64*4;         // N*8
static constexpr size_t OFF_AD1  = OFF_AS1  + (size_t)NN*8*4;
static constexpr size_t OFF_AS2  = OFF_AD1  + (size_t)NN*8*4;
static constexpr size_t OFF_AD2  = OFF_AS2  + (size_t)NN*8*4;
static constexpr size_t OFF_WS2  = OFF_AD2  + (size_t)NN*8*4;          // 512 f32
static constexpr size_t OFF_WD2  = OFF_WS2  + 512*4;
static constexpr size_t OFF_HIST = OFF_WD2  + 512*4;                   // N int
static constexpr size_t OFF_INC  = OFF_HIST + (size_t)NN*4;            // N int
static constexpr size_t OFF_PART = OFF_INC  + (size_t)NN*4;            // 128 int
static constexpr size_t OFF_OFFS = OFF_PART + 128*4;                   // 128 int
static constexpr size_t OFF_RP   = OFF_OFFS + 128*4;                   // N+1 int
static constexpr size_t OFF_CUR  = OFF_RP   + (size_t)(NN+1)*4;        // N int
static constexpr size_t OFF_SRC  = OFF_CUR  + (size_t)NN*4;            // ET int
static constexpr size_t OFF_AGG  = ((OFF_SRC + (size_t)ET*4 + 255) & ~(size_t)255); // N*512 f32

// ---------------- GEMM1: h1 = x[N,256] @ W1[256,64] ----------------
__global__ __launch_bounds__(256) void k_gemm1(const float* __restrict__ x,
                                               const float* __restrict__ W1,
                                               float* __restrict__ h1) {
  __shared__ float xs[128 * 68];
  __shared__ float wsh[64 * 64];
  const int t = threadIdx.x;
  const int lane = t & 63;
  const int wv = t >> 6;
  const int row0 = blockIdx.x * 128;
  float acc[32];
#pragma unroll
  for (int i = 0; i < 32; i++) acc[i] = 0.f;
  for (int kt = 0; kt < 4; kt++) {
#pragma unroll
    for (int i = 0; i < 8; i++) {           // stage x tile 128x64
      int s = i * 256 + t;
      int row = s >> 4, c4 = s & 15;
      float4 v = make_float4(0.f, 0.f, 0.f, 0.f);
      if (row0 + row < NN) v = ((const float4*)x)[(size_t)(row0 + row) * 64 + kt * 16 + c4];
      *((float4*)&xs[row * 68 + c4 * 4]) = v;
    }
#pragma unroll
    for (int i = 0; i < 4; i++) {           // stage W1 tile 64x64
      int s = i * 256 + t;
      int k = s >> 4, c4 = s & 15;
      float4 v = ((const float4*)W1)[(kt * 64 + k) * 16 + c4];
      *((float4*)&wsh[k * 64 + c4 * 4]) = v;
    }
    __syncthreads();
    for (int k4 = 0; k4 < 16; k4++) {
      float w0 = wsh[(k4 * 4 + 0) * 64 + lane];
      float w1 = wsh[(k4 * 4 + 1) * 64 + lane];
      float w2 = wsh[(k4 * 4 + 2) * 64 + lane];
      float w3 = wsh[(k4 * 4 + 3) * 64 + lane];
#pragma unroll
      for (int i = 0; i < 32; i++) {
        float4 xv = *((const float4*)&xs[(wv * 32 + i) * 68 + k4 * 4]);
        acc[i] += xv.x * w0 + xv.y * w1 + xv.z * w2 + xv.w * w3;
      }
    }
    __syncthreads();
  }
#pragma unroll
  for (int i = 0; i < 32; i++) {
    int row = row0 + wv * 32 + i;
    if (row < NN) h1[(size_t)row * 64 + lane] = acc[i];
  }
}

// ---------------- layer-1 attention logits per node ----------------
__global__ void k_alpha1(const float* __restrict__ h1, const float* __restrict__ a_src1,
                         const float* __restrict__ a_dst1, float* __restrict__ as1,
                         float* __restrict__ ad1) {
  int g = blockIdx.x * 256 + threadIdx.x;
  if (g >= NN * 8) return;
  int n = g >> 3, h = g & 7;
  float s = 0.f, d = 0.f;
#pragma unroll
  for (int f = 0; f < 8; f++) {
    float v = h1[(size_t)n * 64 + h * 8 + f];
    s += v * a_src1[h * 8 + f];
    d += v * a_dst1[h * 8 + f];
  }
  as1[g] = s;
  ad1[g] = d;
}

// ---------------- project a_src2/a_dst2 through W2: [64,8] each ----------------
__global__ void k_w2proj(const float* __restrict__ W2, const float* __restrict__ a_src2,
                         const float* __restrict__ a_dst2, float* __restrict__ ws2,
                         float* __restrict__ wd2) {
  int t = threadIdx.x;  // 512 threads: t = k*8+h
  int k = t >> 3, h = t & 7;
  float s = 0.f, d = 0.f;
  for (int f = 0; f < 64; f++) {
    float w = W2[k * 512 + h * 64 + f];
    s += w * a_src2[h * 64 + f];
    d += w * a_dst2[h * 64 + f];
  }
  ws2[t] = s;
  wd2[t] = d;
}

// ---------------- counting sort by dst ----------------
__global__ void k_hist(const int* __restrict__ edge, int* __restrict__ hist) {
  int e = blockIdx.x * 256 + threadIdx.x;
  if (e >= ET) return;
  int d = (e < EE) ? edge[EE + e] : (e - EE);
  atomicAdd(&hist[d], 1);
}

__global__ void k_scan_a(const int* __restrict__ hist, int* __restrict__ inc,
                         int* __restrict__ part) {
  __shared__ int sm[1024];
  int t = threadIdx.x, c = blockIdx.x;
  int i = c * 1024 + t;
  int v = (i < NN) ? hist[i] : 0;
  sm[t] = v;
  for (int off = 1; off < 1024; off <<= 1) {
    __syncthreads();
    int a = (t >= off) ? sm[t - off] : 0;
    __syncthreads();
    sm[t] += a;
  }
  if (i < NN) inc[i] = sm[t];
  if (t == 1023) part[c] = sm[1023];
}

__global__ void k_scan_b(const int* __restrict__ part, int* __restrict__ offs) {
  if (threadIdx.x == 0 && blockIdx.x == 0) {
    int run = 0;
    for (int c = 0; c < NCH; c++) {
      offs[c] = run;
      run += part[c];
    }
  }
}

__global__ void k_scan_c(const int* __restrict__ hist, const int* __restrict__ inc,
                         const int* __restrict__ offs, int* __restrict__ rp,
                         int* __restrict__ cur) {
  int t = threadIdx.x, c = blockIdx.x;
  int i = c * 1024 + t;
  if (i < NN) {
    int r = inc[i] - hist[i] + offs[c];
    rp[i] = r;
    cur[i] = r;
  }
  if (i == 0) rp[NN] = ET;
}

__global__ void k_scatter(const int* __restrict__ edge, int* __restrict__ cur,
                          int* __restrict__ ssrc) {
  int e = blockIdx.x * 256 + threadIdx.x;
  if (e >= ET) return;
  int s, d;
  if (e < EE) { s = edge[e]; d = edge[EE + e]; } else { s = e - EE; d = s; }
  int pos = atomicAdd(&cur[d], 1);
  ssrc[pos] = s;
}

// ---------------- layer-1 aggregation (no-max softmax, edge-parallel weights) ----------------
// Per 64-edge chunk: lane j computes exp-weights p[8] for edge j (1 exp/head/edge),
// stashes (s, p[0..7]) in per-wave LDS; then the wave aggregates serially with
// broadcast ds_reads + coalesced 256B gathers. Denominator reduced once at the end.
__global__ __launch_bounds__(256) void k_aggB1(
    const float* __restrict__ h1, const float* __restrict__ as1,
    const float* __restrict__ ad1, const float* __restrict__ b1,
    const int* __restrict__ rp, const int* __restrict__ ssrc,
    const float* __restrict__ ws2, const float* __restrict__ wd2,
    float* __restrict__ helu, float* __restrict__ as2, float* __restrict__ ad2) {
  __shared__ float lds_p[4][512];
  __shared__ int   lds_s[4][64];
  const int lane = threadIdx.x & 63;
  const int wv = threadIdx.x >> 6;
  const int d = blockIdx.x * 4 + wv;
  if (d >= NN) return;
  const int hl = lane >> 3;  // lane's head (concat layout: lane = h*8+f)
  float4 a0 = ((const float4*)ad1)[d * 2];
  float4 a1 = ((const float4*)ad1)[d * 2 + 1];
  const float adv[8] = {a0.x, a0.y, a0.z, a0.w, a1.x, a1.y, a1.z, a1.w};
  const int r0 = rp[d], r1 = rp[d + 1];
  float l[8];
#pragma unroll
  for (int h = 0; h < 8; h++) l[h] = 0.f;
  float acc = 0.f;
  for (int base = r0; base < r1; base += 64) {
    int idx = base + lane;
    float p[8];
    int s = 0;
    if (idx < r1) {
      s = ssrc[idx];
      float4 s0 = ((const float4*)as1)[s * 2];
      float4 s1 = ((const float4*)as1)[s * 2 + 1];
      float ev[8] = {s0.x + adv[0], s0.y + adv[1], s0.z + adv[2], s0.w + adv[3],
                     s1.x + adv[4], s1.y + adv[5], s1.z + adv[6], s1.w + adv[7]};
#pragma unroll
      for (int h = 0; h < 8; h++) {
        float e = ev[h];
        e = e > 0.f ? e : NEG * e;
        p[h] = __expf(e);
        l[h] += p[h];
      }
    } else {
#pragma unroll
      for (int h = 0; h < 8; h++) p[h] = 0.f;
    }
    lds_s[wv][lane] = s;
    *((float4*)&lds_p[wv][lane * 8]) = make_float4(p[0], p[1], p[2], p[3]);
    *((float4*)&lds_p[wv][lane * 8 + 4]) = make_float4(p[4], p[5], p[6], p[7]);
    int n = min(64, r1 - base);
    for (int j = 0; j < n; j++) {
      int sj = lds_s[wv][j];
      float w = lds_p[wv][j * 8 + hl];
      float g = h1[(size_t)sj * 64 + lane];
      acc += w * g;
    }
  }
  // butterfly-reduce denominators across lanes (all lanes end with all 8 sums)
#pragma unroll
  for (int h = 0; h < 8; h++) {
#pragma unroll
    for (int off = 32; off; off >>= 1) l[h] += __shfl_xor(l[h], off, 64);
  }
  float lv = l[0];
  lv = (hl == 1) ? l[1] : lv;
  lv = (hl == 2) ? l[2] : lv;
  lv = (hl == 3) ? l[3] : lv;
  lv = (hl == 4) ? l[4] : lv;
  lv = (hl == 5) ? l[5] : lv;
  lv = (hl == 6) ? l[6] : lv;
  lv = (hl == 7) ? l[7] : lv;
  float val = acc / lv + b1[lane];
  val = val > 0.f ? val : __expf(val) - 1.f;  // ELU
  helu[(size_t)d * 64 + lane] = val;
  // layer-2 logits: as2[d,h] = sum_k helu[d,k]*ws2[k,h]
#pragma unroll
  for (int h = 0; h < 8; h++) {
    float ps = val * ws2[lane * 8 + h];
    float pd = val * wd2[lane * 8 + h];
#pragma unroll
    for (int off = 32; off; off >>= 1) {
      ps += __shfl_xor(ps, off, 64);
      pd += __shfl_xor(pd, off, 64);
    }
    if (lane == 0) {
      as2[d * 8 + h] = ps;
      ad2[d * 8 + h] = pd;
    }
  }
}

// ---------------- layer-2 aggregation in 64-dim space (deferred matmul) ----------------
__global__ __launch_bounds__(256) void k_aggB2(
    const float* __restrict__ helu, const float* __restrict__ as2,
    const float* __restrict__ ad2, const int* __restrict__ rp,
    const int* __restrict__ ssrc, float* __restrict__ agg) {
  __shared__ float lds_p[4][512];
  __shared__ int   lds_s[4][64];
  const int lane = threadIdx.x & 63;
  const int wv = threadIdx.x >> 6;
  const int d = blockIdx.x * 4 + wv;
  if (d >= NN) return;
  float4 a0 = ((const float4*)ad2)[d * 2];
  float4 a1 = ((const float4*)ad2)[d * 2 + 1];
  const float adv[8] = {a0.x, a0.y, a0.z, a0.w, a1.x, a1.y, a1.z, a1.w};
  const int r0 = rp[d], r1 = rp[d + 1];
  float l[8], acc[8];
#pragma unroll
  for (int h = 0; h < 8; h++) { l[h] = 0.f; acc[h] = 0.f; }
  for (int base = r0; base < r1; base += 64) {
    int idx = base + lane;
    float p[8];
    int s = 0;
    if (idx < r1) {
      s = ssrc[idx];
      float4 s0 = ((const float4*)as2)[s * 2];
      float4 s1 = ((const float4*)as2)[s * 2 + 1];
      float ev[8] = {s0.x + adv[0], s0.y + adv[1], s0.z + adv[2], s0.w + adv[3],
                     s1.x + adv[4], s1.y + adv[5], s1.z + adv[6], s1.w + adv[7]};
#pragma unroll
      for (int h = 0; h < 8; h++) {
        float e = ev[h];
        e = e > 0.f ? e : NEG * e;
        p[h] = __expf(e);
        l[h] += p[h];
      }
    } else {
#pragma unroll
      for (int h = 0; h < 8; h++) p[h] = 0.f;
    }
    lds_s[wv][lane] = s;
    *((float4*)&lds_p[wv][lane * 8]) = make_float4(p[0], p[1], p[2], p[3]);
    *((float4*)&lds_p[wv][lane * 8 + 4]) = make_float4(p[4], p[5], p[6], p[7]);
    int n = min(64, r1 - base);
    for (int j = 0; j < n; j++) {
      int sj = lds_s[wv][j];
      float g = helu[(size_t)sj * 64 + lane];
      float4 w0 = *((const float4*)&lds_p[wv][j * 8]);
      float4 w1 = *((const float4*)&lds_p[wv][j * 8 + 4]);
      acc[0] += w0.x * g;
      acc[1] += w0.y * g;
      acc[2] += w0.z * g;
      acc[3] += w0.w * g;
      acc[4] += w1.x * g;
      acc[5] += w1.y * g;
      acc[6] += w1.z * g;
      acc[7] += w1.w * g;
    }
  }
#pragma unroll
  for (int h = 0; h < 8; h++) {
#pragma unroll
    for (int off = 32; off; off >>= 1) l[h] += __shfl_xor(l[h], off, 64);
  }
#pragma unroll
  for (int h = 0; h < 8; h++) agg[(size_t)d * 512 + h * 64 + lane] = acc[h] / l[h];
}

// ---------------- GEMM2: out = (1/8)*agg[N,512] @ W2'[512,64] + b2 ----------------
// W2'[h*64+kk][f] = W2[kk][h*64+f]; with 64-aligned K-tiles, h == kt.
__global__ __launch_bounds__(256) void k_gemm2(const float* __restrict__ agg,
                                               const float* __restrict__ W2,
                                               const float* __restrict__ b2,
                                               float* __restrict__ out) {
  __shared__ float xs[128 * 68];
  __shared__ float wsh[64 * 64];
  const int t = threadIdx.x;
  const int lane = t & 63;
  const int wv = t >> 6;
  const int row0 = blockIdx.x * 128;
  float acc[32];
#pragma unroll
  for (int i = 0; i < 32; i++) acc[i] = 0.f;
  for (int kt = 0; kt < 8; kt++) {
#pragma unroll
    for (int i = 0; i < 8; i++) {  // stage agg tile 128x64
      int s = i * 256 + t;
      int row = s >> 4, c4 = s & 15;
      float4 v = make_float4(0.f, 0.f, 0.f, 0.f);
      if (row0 + row < NN) v = ((const float4*)agg)[(size_t)(row0 + row) * 128 + kt * 16 + c4];
      *((float4*)&xs[row * 68 + c4 * 4]) = v;
    }
#pragma unroll
    for (int i = 0; i < 4; i++) {  // stage W2 block (h=kt): [kk=0..63][f=0..63]
      int s = i * 256 + t;
      int k = s >> 4, c4 = s & 15;
      float4 v = ((const float4*)W2)[(size_t)k * 128 + kt * 16 + c4];
      *((float4*)&wsh[k * 64 + c4 * 4]) = v;
    }
    __syncthreads();
    for (int k4 = 0; k4 < 16; k4++) {
      float w0 = wsh[(k4 * 4 + 0) * 64 + lane];
      float w1 = wsh[(k4 * 4 + 1) * 64 + lane];
      float w2 = wsh[(k4 * 4 + 2) * 64 + lane];
      float w3 = wsh[(k4 * 4 + 3) * 64 + lane];
#pragma unroll
      for (int i = 0; i < 32; i++) {
        float4 xv = *((const float4*)&xs[(wv * 32 + i) * 68 + k4 * 4]);
        acc[i] += xv.x * w0 + xv.y * w1 + xv.z * w2 + xv.w * w3;
      }
    }
    __syncthreads();
  }
  float bb = b2[lane];
#pragma unroll
  for (int i = 0; i < 32; i++) {
    int row = row0 + wv * 32 + i;
    if (row < NN) out[(size_t)row * 64 + lane] = 0.125f * acc[i] + bb;
  }
}

extern "C" void kernel_launch(void* const* d_in, const int* in_sizes, int n_in,
                              void* d_out, int out_size, void* d_ws, size_t ws_size,
                              hipStream_t stream) {
  const float* x      = (const float*)d_in[0];
  const float* W1     = (const float*)d_in[1];
  const float* a_src1 = (const float*)d_in[2];
  const float* a_dst1 = (const float*)d_in[3];
  const float* b1     = (const float*)d_in[4];
  const float* W2     = (const float*)d_in[5];
  const float* a_src2 = (const float*)d_in[6];
  const float* a_dst2 = (const float*)d_in[7];
  const float* b2     = (const float*)d_in[8];
  const int*   edge   = (const int*)d_in[9];

  char* ws = (char*)d_ws;
  float* h1   = (float*)(ws + OFF_H1);
  float* helu = (float*)(ws + OFF_HELU);
  float* as1  = (float*)(ws + OFF_AS1);
  float* ad1  = (float*)(ws + OFF_AD1);
  float* as2  = (float*)(ws + OFF_AS2);
  float* ad2  = (float*)(ws + OFF_AD2);
  float* ws2  = (float*)(ws + OFF_WS2);
  float* wd2  = (float*)(ws + OFF_WD2);
  int* hist   = (int*)(ws + OFF_HIST);
  int* inc    = (int*)(ws + OFF_INC);
  int* part   = (int*)(ws + OFF_PART);
  int* offs   = (int*)(ws + OFF_OFFS);
  int* rp     = (int*)(ws + OFF_RP);
  int* cur    = (int*)(ws + OFF_CUR);
  int* ssrc   = (int*)(ws + OFF_SRC);
  float* agg  = (float*)(ws + OFF_AGG);
  float* out  = (float*)d_out;

  hipMemsetAsync(hist, 0, (size_t)NN * 4, stream);

  k_gemm1<<<(NN + 127) / 128, 256, 0, stream>>>(x, W1, h1);
  k_alpha1<<<(NN * 8 + 255) / 256, 256, 0, stream>>>(h1, a_src1, a_dst1, as1, ad1);
  k_w2proj<<<1, 512, 0, stream>>>(W2, a_src2, a_dst2, ws2, wd2);
  k_hist<<<(ET + 255) / 256, 256, 0, stream>>>(edge, hist);
  k_scan_a<<<NCH, 1024, 0, stream>>>(hist, inc, part);
  k_scan_b<<<1, 64, 0, stream>>>(part, offs);
  k_scan_c<<<NCH, 1024, 0, stream>>>(hist, inc, offs, rp, cur);
  k_scatter<<<(ET + 255) / 256, 256, 0, stream>>>(edge, cur, ssrc);
  k_aggB1<<<(NN + 3) / 4, 256, 0, stream>>>(h1, as1, ad1, b1, rp, ssrc, ws2, wd2, helu, as2, ad2);
  k_aggB2<<<(NN + 3) / 4, 256, 0, stream>>>(helu, as2, ad2, rp, ssrc, agg);
  k_gemm2<<<(NN + 127) / 128, 256, 0, stream>>>(agg, W2, b2, out);
}

// Round 3
// 1039.937 us; speedup vs baseline: 1.3809x; 1.1048x over previous
//
#include <hip/hip_runtime.h>
#include <math.h>

#define NN 100000
#define EE 1600000
#define ET 1700000   // EE + NN self loops
#define NEG 0.2f
#define NCH 98       // ceil(NN/1024)

// ---------------- ws layout (bytes) ----------------
static constexpr size_t OFF_H1   = 0;                                  // N*64 f32
static constexpr size_t OFF_HELU = OFF_H1   + (size_t)NN*64*4;         // N*64 f32
static constexpr size_t OFF_AS1  = OFF_HELU + (size_t)NN*64*4;         // N*8
static constexpr size_t OFF_AD1  = OFF_AS1  + (size_t)NN*8*4;
static constexpr size_t OFF_AS2  = OFF_AD1  + (size_t)NN*8*4;
static constexpr size_t OFF_AD2  = OFF_AS2  + (size_t)NN*8*4;
static constexpr size_t OFF_WS2  = OFF_AD2  + (size_t)NN*8*4;          // 512 f32
static constexpr size_t OFF_WD2  = OFF_WS2  + 512*4;
static constexpr size_t OFF_HIST = OFF_WD2  + 512*4;                   // N int
static constexpr size_t OFF_INC  = OFF_HIST + (size_t)NN*4;            // N int
static constexpr size_t OFF_PART = OFF_INC  + (size_t)NN*4;            // 128 int
static constexpr size_t OFF_OFFS = OFF_PART + 128*4;                   // 128 int
static constexpr size_t OFF_RP   = OFF_OFFS + 128*4;                   // N+1 int
static constexpr size_t OFF_CUR  = OFF_RP   + (size_t)(NN+1)*4;        // N int
static constexpr size_t OFF_SRC  = OFF_CUR  + (size_t)NN*4;            // ET int
static constexpr size_t OFF_AGG  = ((OFF_SRC + (size_t)ET*4 + 255) & ~(size_t)255); // N*512 f32

// ---------------- GEMM1: h1 = x[N,256] @ W1[256,64], fused as1/ad1 epilogue ----
// 128 threads = 2 waves; block tile 128 rows x 64 cols; lane tile 8x8.
// lane = lr*8+lc is WRONG; we use lr=lane>>3 (row group), lc=lane&7 (col group).
// Lane rows: wv*64 + lr + 8*i (i=0..7); lane cols: lc*8 .. lc*8+7 (== head lc).
__global__ __launch_bounds__(128) void k_gemm1(const float* __restrict__ x,
                                               const float* __restrict__ W1,
                                               const float* __restrict__ a_src1,
                                               const float* __restrict__ a_dst1,
                                               float* __restrict__ h1,
                                               float* __restrict__ as1,
                                               float* __restrict__ ad1) {
  __shared__ float xs[128 * 36];   // pitch 36: row stride mod 32 = 4 -> conflict-free
  __shared__ float wsh[32 * 64];
  const int t = threadIdx.x;
  const int lane = t & 63;
  const int wv = t >> 6;
  const int lr = lane >> 3;
  const int lc = lane & 7;
  const int row0 = blockIdx.x * 128;
  float acc[8][8];
#pragma unroll
  for (int i = 0; i < 8; i++)
#pragma unroll
    for (int j = 0; j < 8; j++) acc[i][j] = 0.f;

  for (int kt = 0; kt < 8; kt++) {
#pragma unroll
    for (int i = 0; i < 8; i++) {            // stage x tile 128x32
      int s = i * 128 + t;
      int row = s >> 3, c4 = s & 7;
      float4 v = make_float4(0.f, 0.f, 0.f, 0.f);
      if (row0 + row < NN) v = ((const float4*)x)[(size_t)(row0 + row) * 64 + kt * 8 + c4];
      *((float4*)&xs[row * 36 + c4 * 4]) = v;
    }
#pragma unroll
    for (int i = 0; i < 4; i++) {            // stage W1 tile 32x64
      int s = i * 128 + t;
      int k = s >> 4, c4 = s & 15;
      float4 v = ((const float4*)W1)[(kt * 32 + k) * 16 + c4];
      *((float4*)&wsh[k * 64 + c4 * 4]) = v;
    }
    __syncthreads();
#pragma unroll
    for (int k4 = 0; k4 < 8; k4++) {
      float4 a[8];
#pragma unroll
      for (int i = 0; i < 8; i++)
        a[i] = *((const float4*)&xs[(wv * 64 + lr + 8 * i) * 36 + k4 * 4]);
#pragma unroll
      for (int kk = 0; kk < 4; kk++) {
        float4 bl = *((const float4*)&wsh[(k4 * 4 + kk) * 64 + lc * 8]);
        float4 bh = *((const float4*)&wsh[(k4 * 4 + kk) * 64 + lc * 8 + 4]);
#pragma unroll
        for (int i = 0; i < 8; i++) {
          float av = ((const float*)&a[i])[kk];
          acc[i][0] += av * bl.x; acc[i][1] += av * bl.y;
          acc[i][2] += av * bl.z; acc[i][3] += av * bl.w;
          acc[i][4] += av * bh.x; acc[i][5] += av * bh.y;
          acc[i][6] += av * bh.z; acc[i][7] += av * bh.w;
        }
      }
    }
    __syncthreads();
  }
  // epilogue: store h1 + fused attention logits (head == lc, lane-local dot)
  float4 s0 = ((const float4*)a_src1)[lc * 2];
  float4 s1 = ((const float4*)a_src1)[lc * 2 + 1];
  float4 d0 = ((const float4*)a_dst1)[lc * 2];
  float4 d1 = ((const float4*)a_dst1)[lc * 2 + 1];
#pragma unroll
  for (int i = 0; i < 8; i++) {
    int row = row0 + wv * 64 + lr + 8 * i;
    if (row >= NN) continue;
    ((float4*)h1)[(size_t)row * 16 + lc * 2]     = make_float4(acc[i][0], acc[i][1], acc[i][2], acc[i][3]);
    ((float4*)h1)[(size_t)row * 16 + lc * 2 + 1] = make_float4(acc[i][4], acc[i][5], acc[i][6], acc[i][7]);
    float sd = acc[i][0] * s0.x + acc[i][1] * s0.y + acc[i][2] * s0.z + acc[i][3] * s0.w
             + acc[i][4] * s1.x + acc[i][5] * s1.y + acc[i][6] * s1.z + acc[i][7] * s1.w;
    float dd = acc[i][0] * d0.x + acc[i][1] * d0.y + acc[i][2] * d0.z + acc[i][3] * d0.w
             + acc[i][4] * d1.x + acc[i][5] * d1.y + acc[i][6] * d1.z + acc[i][7] * d1.w;
    as1[row * 8 + lc] = sd;
    ad1[row * 8 + lc] = dd;
  }
}

// ---------------- project a_src2/a_dst2 through W2: [64,8] each ----------------
__global__ void k_w2proj(const float* __restrict__ W2, const float* __restrict__ a_src2,
                         const float* __restrict__ a_dst2, float* __restrict__ ws2,
                         float* __restrict__ wd2) {
  int t = threadIdx.x;  // 512 threads: t = k*8+h
  int k = t >> 3, h = t & 7;
  float s = 0.f, d = 0.f;
  for (int f = 0; f < 64; f++) {
    float w = W2[k * 512 + h * 64 + f];
    s += w * a_src2[h * 64 + f];
    d += w * a_dst2[h * 64 + f];
  }
  ws2[t] = s;
  wd2[t] = d;
}

// ---------------- counting sort by dst ----------------
__global__ void k_hist(const int* __restrict__ edge, int* __restrict__ hist) {
  int e = blockIdx.x * 256 + threadIdx.x;
  if (e >= ET) return;
  int d = (e < EE) ? edge[EE + e] : (e - EE);
  atomicAdd(&hist[d], 1);
}

__global__ void k_scan_a(const int* __restrict__ hist, int* __restrict__ inc,
                         int* __restrict__ part) {
  __shared__ int sm[1024];
  int t = threadIdx.x, c = blockIdx.x;
  int i = c * 1024 + t;
  int v = (i < NN) ? hist[i] : 0;
  sm[t] = v;
  for (int off = 1; off < 1024; off <<= 1) {
    __syncthreads();
    int a = (t >= off) ? sm[t - off] : 0;
    __syncthreads();
    sm[t] += a;
  }
  if (i < NN) inc[i] = sm[t];
  if (t == 1023) part[c] = sm[1023];
}

__global__ void k_scan_b(const int* __restrict__ part, int* __restrict__ offs) {
  if (threadIdx.x == 0 && blockIdx.x == 0) {
    int run = 0;
    for (int c = 0; c < NCH; c++) {
      offs[c] = run;
      run += part[c];
    }
  }
}

__global__ void k_scan_c(const int* __restrict__ hist, const int* __restrict__ inc,
                         const int* __restrict__ offs, int* __restrict__ rp,
                         int* __restrict__ cur) {
  int t = threadIdx.x, c = blockIdx.x;
  int i = c * 1024 + t;
  if (i < NN) {
    int r = inc[i] - hist[i] + offs[c];
    rp[i] = r;
    cur[i] = r;
  }
  if (i == 0) rp[NN] = ET;
}

__global__ void k_scatter(const int* __restrict__ edge, int* __restrict__ cur,
                          int* __restrict__ ssrc) {
  int e = blockIdx.x * 256 + threadIdx.x;
  if (e >= ET) return;
  int s, d;
  if (e < EE) { s = edge[e]; d = edge[EE + e]; } else { s = e - EE; d = s; }
  int pos = atomicAdd(&cur[d], 1);
  ssrc[pos] = s;
}

// ---------------- layer-1 aggregation (no-max softmax, edge-parallel weights) ----------------
__global__ __launch_bounds__(256) void k_aggB1(
    const float* __restrict__ h1, const float* __restrict__ as1,
    const float* __restrict__ ad1, const float* __restrict__ b1,
    const int* __restrict__ rp, const int* __restrict__ ssrc,
    const float* __restrict__ ws2, const float* __restrict__ wd2,
    float* __restrict__ helu, float* __restrict__ as2, float* __restrict__ ad2) {
  __shared__ float lds_p[4][512];
  __shared__ int   lds_s[4][64];
  const int lane = threadIdx.x & 63;
  const int wv = threadIdx.x >> 6;
  const int d = blockIdx.x * 4 + wv;
  if (d >= NN) return;
  const int hl = lane >> 3;  // lane's head (concat layout: lane = h*8+f)
  float4 a0 = ((const float4*)ad1)[d * 2];
  float4 a1 = ((const float4*)ad1)[d * 2 + 1];
  const float adv[8] = {a0.x, a0.y, a0.z, a0.w, a1.x, a1.y, a1.z, a1.w};
  const int r0 = rp[d], r1 = rp[d + 1];
  float l[8];
#pragma unroll
  for (int h = 0; h < 8; h++) l[h] = 0.f;
  float acc = 0.f;
  for (int base = r0; base < r1; base += 64) {
    int idx = base + lane;
    float p[8];
    int s = 0;
    if (idx < r1) {
      s = ssrc[idx];
      float4 s0 = ((const float4*)as1)[s * 2];
      float4 s1 = ((const float4*)as1)[s * 2 + 1];
      float ev[8] = {s0.x + adv[0], s0.y + adv[1], s0.z + adv[2], s0.w + adv[3],
                     s1.x + adv[4], s1.y + adv[5], s1.z + adv[6], s1.w + adv[7]};
#pragma unroll
      for (int h = 0; h < 8; h++) {
        float e = ev[h];
        e = e > 0.f ? e : NEG * e;
        p[h] = __expf(e);
        l[h] += p[h];
      }
    } else {
#pragma unroll
      for (int h = 0; h < 8; h++) p[h] = 0.f;
    }
    lds_s[wv][lane] = s;
    *((float4*)&lds_p[wv][lane * 8]) = make_float4(p[0], p[1], p[2], p[3]);
    *((float4*)&lds_p[wv][lane * 8 + 4]) = make_float4(p[4], p[5], p[6], p[7]);
    int n = min(64, r1 - base);
    for (int j = 0; j < n; j++) {
      int sj = lds_s[wv][j];
      float w = lds_p[wv][j * 8 + hl];
      float g = h1[(size_t)sj * 64 + lane];
      acc += w * g;
    }
  }
#pragma unroll
  for (int h = 0; h < 8; h++) {
#pragma unroll
    for (int off = 32; off; off >>= 1) l[h] += __shfl_xor(l[h], off, 64);
  }
  float lv = l[0];
  lv = (hl == 1) ? l[1] : lv;
  lv = (hl == 2) ? l[2] : lv;
  lv = (hl == 3) ? l[3] : lv;
  lv = (hl == 4) ? l[4] : lv;
  lv = (hl == 5) ? l[5] : lv;
  lv = (hl == 6) ? l[6] : lv;
  lv = (hl == 7) ? l[7] : lv;
  float val = acc / lv + b1[lane];
  val = val > 0.f ? val : __expf(val) - 1.f;  // ELU
  helu[(size_t)d * 64 + lane] = val;
#pragma unroll
  for (int h = 0; h < 8; h++) {
    float ps = val * ws2[lane * 8 + h];
    float pd = val * wd2[lane * 8 + h];
#pragma unroll
    for (int off = 32; off; off >>= 1) {
      ps += __shfl_xor(ps, off, 64);
      pd += __shfl_xor(pd, off, 64);
    }
    if (lane == 0) {
      as2[d * 8 + h] = ps;
      ad2[d * 8 + h] = pd;
    }
  }
}

// ---------------- layer-2 aggregation in 64-dim space (deferred matmul) ----------------
__global__ __launch_bounds__(256) void k_aggB2(
    const float* __restrict__ helu, const float* __restrict__ as2,
    const float* __restrict__ ad2, const int* __restrict__ rp,
    const int* __restrict__ ssrc, float* __restrict__ agg) {
  __shared__ float lds_p[4][512];
  __shared__ int   lds_s[4][64];
  const int lane = threadIdx.x & 63;
  const int wv = threadIdx.x >> 6;
  const int d = blockIdx.x * 4 + wv;
  if (d >= NN) return;
  float4 a0 = ((const float4*)ad2)[d * 2];
  float4 a1 = ((const float4*)ad2)[d * 2 + 1];
  const float adv[8] = {a0.x, a0.y, a0.z, a0.w, a1.x, a1.y, a1.z, a1.w};
  const int r0 = rp[d], r1 = rp[d + 1];
  float l[8], acc[8];
#pragma unroll
  for (int h = 0; h < 8; h++) { l[h] = 0.f; acc[h] = 0.f; }
  for (int base = r0; base < r1; base += 64) {
    int idx = base + lane;
    float p[8];
    int s = 0;
    if (idx < r1) {
      s = ssrc[idx];
      float4 s0 = ((const float4*)as2)[s * 2];
      float4 s1 = ((const float4*)as2)[s * 2 + 1];
      float ev[8] = {s0.x + adv[0], s0.y + adv[1], s0.z + adv[2], s0.w + adv[3],
                     s1.x + adv[4], s1.y + adv[5], s1.z + adv[6], s1.w + adv[7]};
#pragma unroll
      for (int h = 0; h < 8; h++) {
        float e = ev[h];
        e = e > 0.f ? e : NEG * e;
        p[h] = __expf(e);
        l[h] += p[h];
      }
    } else {
#pragma unroll
      for (int h = 0; h < 8; h++) p[h] = 0.f;
    }
    lds_s[wv][lane] = s;
    *((float4*)&lds_p[wv][lane * 8]) = make_float4(p[0], p[1], p[2], p[3]);
    *((float4*)&lds_p[wv][lane * 8 + 4]) = make_float4(p[4], p[5], p[6], p[7]);
    int n = min(64, r1 - base);
    for (int j = 0; j < n; j++) {
      int sj = lds_s[wv][j];
      float g = helu[(size_t)sj * 64 + lane];
      float4 w0 = *((const float4*)&lds_p[wv][j * 8]);
      float4 w1 = *((const float4*)&lds_p[wv][j * 8 + 4]);
      acc[0] += w0.x * g;
      acc[1] += w0.y * g;
      acc[2] += w0.z * g;
      acc[3] += w0.w * g;
      acc[4] += w1.x * g;
      acc[5] += w1.y * g;
      acc[6] += w1.z * g;
      acc[7] += w1.w * g;
    }
  }
#pragma unroll
  for (int h = 0; h < 8; h++) {
#pragma unroll
    for (int off = 32; off; off >>= 1) l[h] += __shfl_xor(l[h], off, 64);
  }
#pragma unroll
  for (int h = 0; h < 8; h++) agg[(size_t)d * 512 + h * 64 + lane] = acc[h] / l[h];
}

// ---------------- GEMM2: out = (1/8)*agg[N,512] @ W2'[512,64] + b2 ----------------
// W2'[h*64+kk][f] = W2[kk][h*64+f]; K-tile 32: kt = h*2+p, kk = p*32+k.
__global__ __launch_bounds__(128) void k_gemm2(const float* __restrict__ agg,
                                               const float* __restrict__ W2,
                                               const float* __restrict__ b2,
                                               float* __restrict__ out) {
  __shared__ float xs[128 * 36];
  __shared__ float wsh[32 * 64];
  const int t = threadIdx.x;
  const int lane = t & 63;
  const int wv = t >> 6;
  const int lr = lane >> 3;
  const int lc = lane & 7;
  const int row0 = blockIdx.x * 128;
  float acc[8][8];
#pragma unroll
  for (int i = 0; i < 8; i++)
#pragma unroll
    for (int j = 0; j < 8; j++) acc[i][j] = 0.f;

  for (int kt = 0; kt < 16; kt++) {
#pragma unroll
    for (int i = 0; i < 8; i++) {            // stage agg tile 128x32
      int s = i * 128 + t;
      int row = s >> 3, c4 = s & 7;
      float4 v = make_float4(0.f, 0.f, 0.f, 0.f);
      if (row0 + row < NN) v = ((const float4*)agg)[(size_t)(row0 + row) * 128 + kt * 8 + c4];
      *((float4*)&xs[row * 36 + c4 * 4]) = v;
    }
#pragma unroll
    for (int i = 0; i < 4; i++) {            // stage W2 sub-block 32x64
      int s = i * 128 + t;
      int k = s >> 4, c4 = s & 15;
      float4 v = ((const float4*)W2)[(size_t)((kt & 1) * 32 + k) * 128 + (kt >> 1) * 16 + c4];
      *((float4*)&wsh[k * 64 + c4 * 4]) = v;
    }
    __syncthreads();
#pragma unroll
    for (int k4 = 0; k4 < 8; k4++) {
      float4 a[8];
#pragma unroll
      for (int i = 0; i < 8; i++)
        a[i] = *((const float4*)&xs[(wv * 64 + lr + 8 * i) * 36 + k4 * 4]);
#pragma unroll
      for (int kk = 0; kk < 4; kk++) {
        float4 bl = *((const float4*)&wsh[(k4 * 4 + kk) * 64 + lc * 8]);
        float4 bh = *((const float4*)&wsh[(k4 * 4 + kk) * 64 + lc * 8 + 4]);
#pragma unroll
        for (int i = 0; i < 8; i++) {
          float av = ((const float*)&a[i])[kk];
          acc[i][0] += av * bl.x; acc[i][1] += av * bl.y;
          acc[i][2] += av * bl.z; acc[i][3] += av * bl.w;
          acc[i][4] += av * bh.x; acc[i][5] += av * bh.y;
          acc[i][6] += av * bh.z; acc[i][7] += av * bh.w;
        }
      }
    }
    __syncthreads();
  }
  float4 b2l = ((const float4*)b2)[lc * 2];
  float4 b2h = ((const float4*)b2)[lc * 2 + 1];
#pragma unroll
  for (int i = 0; i < 8; i++) {
    int row = row0 + wv * 64 + lr + 8 * i;
    if (row >= NN) continue;
    ((float4*)out)[(size_t)row * 16 + lc * 2] =
        make_float4(0.125f * acc[i][0] + b2l.x, 0.125f * acc[i][1] + b2l.y,
                    0.125f * acc[i][2] + b2l.z, 0.125f * acc[i][3] + b2l.w);
    ((float4*)out)[(size_t)row * 16 + lc * 2 + 1] =
        make_float4(0.125f * acc[i][4] + b2h.x, 0.125f * acc[i][5] + b2h.y,
                    0.125f * acc[i][6] + b2h.z, 0.125f * acc[i][7] + b2h.w);
  }
}

extern "C" void kernel_launch(void* const* d_in, const int* in_sizes, int n_in,
                              void* d_out, int out_size, void* d_ws, size_t ws_size,
                              hipStream_t stream) {
  const float* x      = (const float*)d_in[0];
  const float* W1     = (const float*)d_in[1];
  const float* a_src1 = (const float*)d_in[2];
  const float* a_dst1 = (const float*)d_in[3];
  const float* b1     = (const float*)d_in[4];
  const float* W2     = (const float*)d_in[5];
  const float* a_src2 = (const float*)d_in[6];
  const float* a_dst2 = (const float*)d_in[7];
  const float* b2     = (const float*)d_in[8];
  const int*   edge   = (const int*)d_in[9];

  char* ws = (char*)d_ws;
  float* h1   = (float*)(ws + OFF_H1);
  float* helu = (float*)(ws + OFF_HELU);
  float* as1  = (float*)(ws + OFF_AS1);
  float* ad1  = (float*)(ws + OFF_AD1);
  float* as2  = (float*)(ws + OFF_AS2);
  float* ad2  = (float*)(ws + OFF_AD2);
  float* ws2  = (float*)(ws + OFF_WS2);
  float* wd2  = (float*)(ws + OFF_WD2);
  int* hist   = (int*)(ws + OFF_HIST);
  int* inc    = (int*)(ws + OFF_INC);
  int* part   = (int*)(ws + OFF_PART);
  int* offs   = (int*)(ws + OFF_OFFS);
  int* rp     = (int*)(ws + OFF_RP);
  int* cur    = (int*)(ws + OFF_CUR);
  int* ssrc   = (int*)(ws + OFF_SRC);
  float* agg  = (float*)(ws + OFF_AGG);
  float* out  = (float*)d_out;

  hipMemsetAsync(hist, 0, (size_t)NN * 4, stream);

  k_gemm1<<<(NN + 127) / 128, 128, 0, stream>>>(x, W1, a_src1, a_dst1, h1, as1, ad1);
  k_w2proj<<<1, 512, 0, stream>>>(W2, a_src2, a_dst2, ws2, wd2);
  k_hist<<<(ET + 255) / 256, 256, 0, stream>>>(edge, hist);
  k_scan_a<<<NCH, 1024, 0, stream>>>(hist, inc, part);
  k_scan_b<<<1, 64, 0, stream>>>(part, offs);
  k_scan_c<<<NCH, 1024, 0, stream>>>(hist, inc, offs, rp, cur);
  k_scatter<<<(ET + 255) / 256, 256, 0, stream>>>(edge, cur, ssrc);
  k_aggB1<<<(NN + 3) / 4, 256, 0, stream>>>(h1, as1, ad1, b1, rp, ssrc, ws2, wd2, helu, as2, ad2);
  k_aggB2<<<(NN + 3) / 4, 256, 0, stream>>>(helu, as2, ad2, rp, ssrc, agg);
  k_gemm2<<<(NN + 127) / 128, 128, 0, stream>>>(agg, W2, b2, out);
}

// Round 4
// 1037.326 us; speedup vs baseline: 1.3844x; 1.0025x over previous
//
#include <hip/hip_runtime.h>
#include <math.h>

#define NN 100000
#define EE 1600000
#define ET 1700000   // EE + NN self loops
#define NEG 0.2f
#define NCH 98       // ceil(NN/1024)

// ---------------- ws layout (bytes) ----------------
static constexpr size_t OFF_H1   = 0;                                  // N*64 f32
static constexpr size_t OFF_HELU = OFF_H1   + (size_t)NN*64*4;         // N*64 f32
static constexpr size_t OFF_AS1  = OFF_HELU + (size_t)NN*64*4;         // N*8
static constexpr size_t OFF_AD1  = OFF_AS1  + (size_t)NN*8*4;
static constexpr size_t OFF_AS2  = OFF_AD1  + (size_t)NN*8*4;
static constexpr size_t OFF_AD2  = OFF_AS2  + (size_t)NN*8*4;
static constexpr size_t OFF_WS2  = OFF_AD2  + (size_t)NN*8*4;          // 512 f32
static constexpr size_t OFF_WD2  = OFF_WS2  + 512*4;
static constexpr size_t OFF_HIST = OFF_WD2  + 512*4;                   // N int
static constexpr size_t OFF_INC  = OFF_HIST + (size_t)NN*4;            // N int
static constexpr size_t OFF_PART = OFF_INC  + (size_t)NN*4;            // 128 int
static constexpr size_t OFF_OFFS = OFF_PART + 128*4;                   // 128 int
static constexpr size_t OFF_RP   = OFF_OFFS + 128*4;                   // N+1 int
static constexpr size_t OFF_CUR  = OFF_RP   + (size_t)(NN+1)*4;        // N int
static constexpr size_t OFF_SRC  = OFF_CUR  + (size_t)NN*4;            // ET int
static constexpr size_t OFF_AGG  = ((OFF_SRC + (size_t)ET*4 + 255) & ~(size_t)255); // N*512 f32

// ---------------- GEMM1: h1 = x[N,256] @ W1[256,64], fused as1/ad1 epilogue ----
__global__ __launch_bounds__(128) void k_gemm1(const float* __restrict__ x,
                                               const float* __restrict__ W1,
                                               const float* __restrict__ a_src1,
                                               const float* __restrict__ a_dst1,
                                               float* __restrict__ h1,
                                               float* __restrict__ as1,
                                               float* __restrict__ ad1) {
  __shared__ float xs[128 * 36];   // pitch 36: row stride mod 32 = 4 -> conflict-free
  __shared__ float wsh[32 * 64];
  const int t = threadIdx.x;
  const int lane = t & 63;
  const int wv = t >> 6;
  const int lr = lane >> 3;
  const int lc = lane & 7;
  const int row0 = blockIdx.x * 128;
  float acc[8][8];
#pragma unroll
  for (int i = 0; i < 8; i++)
#pragma unroll
    for (int j = 0; j < 8; j++) acc[i][j] = 0.f;

  for (int kt = 0; kt < 8; kt++) {
#pragma unroll
    for (int i = 0; i < 8; i++) {            // stage x tile 128x32
      int s = i * 128 + t;
      int row = s >> 3, c4 = s & 7;
      float4 v = make_float4(0.f, 0.f, 0.f, 0.f);
      if (row0 + row < NN) v = ((const float4*)x)[(size_t)(row0 + row) * 64 + kt * 8 + c4];
      *((float4*)&xs[row * 36 + c4 * 4]) = v;
    }
#pragma unroll
    for (int i = 0; i < 4; i++) {            // stage W1 tile 32x64
      int s = i * 128 + t;
      int k = s >> 4, c4 = s & 15;
      float4 v = ((const float4*)W1)[(kt * 32 + k) * 16 + c4];
      *((float4*)&wsh[k * 64 + c4 * 4]) = v;
    }
    __syncthreads();
#pragma unroll
    for (int k4 = 0; k4 < 8; k4++) {
      float4 a[8];
#pragma unroll
      for (int i = 0; i < 8; i++)
        a[i] = *((const float4*)&xs[(wv * 64 + lr + 8 * i) * 36 + k4 * 4]);
#pragma unroll
      for (int kk = 0; kk < 4; kk++) {
        float4 bl = *((const float4*)&wsh[(k4 * 4 + kk) * 64 + lc * 8]);
        float4 bh = *((const float4*)&wsh[(k4 * 4 + kk) * 64 + lc * 8 + 4]);
#pragma unroll
        for (int i = 0; i < 8; i++) {
          float av = ((const float*)&a[i])[kk];
          acc[i][0] += av * bl.x; acc[i][1] += av * bl.y;
          acc[i][2] += av * bl.z; acc[i][3] += av * bl.w;
          acc[i][4] += av * bh.x; acc[i][5] += av * bh.y;
          acc[i][6] += av * bh.z; acc[i][7] += av * bh.w;
        }
      }
    }
    __syncthreads();
  }
  float4 s0 = ((const float4*)a_src1)[lc * 2];
  float4 s1 = ((const float4*)a_src1)[lc * 2 + 1];
  float4 d0 = ((const float4*)a_dst1)[lc * 2];
  float4 d1 = ((const float4*)a_dst1)[lc * 2 + 1];
#pragma unroll
  for (int i = 0; i < 8; i++) {
    int row = row0 + wv * 64 + lr + 8 * i;
    if (row >= NN) continue;
    ((float4*)h1)[(size_t)row * 16 + lc * 2]     = make_float4(acc[i][0], acc[i][1], acc[i][2], acc[i][3]);
    ((float4*)h1)[(size_t)row * 16 + lc * 2 + 1] = make_float4(acc[i][4], acc[i][5], acc[i][6], acc[i][7]);
    float sd = acc[i][0] * s0.x + acc[i][1] * s0.y + acc[i][2] * s0.z + acc[i][3] * s0.w
             + acc[i][4] * s1.x + acc[i][5] * s1.y + acc[i][6] * s1.z + acc[i][7] * s1.w;
    float dd = acc[i][0] * d0.x + acc[i][1] * d0.y + acc[i][2] * d0.z + acc[i][3] * d0.w
             + acc[i][4] * d1.x + acc[i][5] * d1.y + acc[i][6] * d1.z + acc[i][7] * d1.w;
    as1[row * 8 + lc] = sd;
    ad1[row * 8 + lc] = dd;
  }
}

// ---------------- project a_src2/a_dst2 through W2: [64,8] each ----------------
__global__ void k_w2proj(const float* __restrict__ W2, const float* __restrict__ a_src2,
                         const float* __restrict__ a_dst2, float* __restrict__ ws2,
                         float* __restrict__ wd2) {
  int t = threadIdx.x;  // 512 threads: t = k*8+h
  int k = t >> 3, h = t & 7;
  float s = 0.f, d = 0.f;
  for (int f = 0; f < 64; f++) {
    float w = W2[k * 512 + h * 64 + f];
    s += w * a_src2[h * 64 + f];
    d += w * a_dst2[h * 64 + f];
  }
  ws2[t] = s;
  wd2[t] = d;
}

// ---------------- counting sort by dst ----------------
__global__ void k_hist(const int* __restrict__ edge, int* __restrict__ hist) {
  int e = blockIdx.x * 256 + threadIdx.x;
  if (e >= ET) return;
  int d = (e < EE) ? edge[EE + e] : (e - EE);
  atomicAdd(&hist[d], 1);
}

__global__ void k_scan_a(const int* __restrict__ hist, int* __restrict__ inc,
                         int* __restrict__ part) {
  __shared__ int sm[1024];
  int t = threadIdx.x, c = blockIdx.x;
  int i = c * 1024 + t;
  int v = (i < NN) ? hist[i] : 0;
  sm[t] = v;
  for (int off = 1; off < 1024; off <<= 1) {
    __syncthreads();
    int a = (t >= off) ? sm[t - off] : 0;
    __syncthreads();
    sm[t] += a;
  }
  if (i < NN) inc[i] = sm[t];
  if (t == 1023) part[c] = sm[1023];
}

__global__ void k_scan_b(const int* __restrict__ part, int* __restrict__ offs) {
  int t = threadIdx.x;  // 128 threads, parallel O(n^2) prefix over 98 entries
  if (t >= 128) return;
  int run = 0;
  for (int c = 0; c < NCH; c++)
    if (c < t) run += part[c];
  if (t < NCH) offs[t] = run;
}

__global__ void k_scan_c(const int* __restrict__ hist, const int* __restrict__ inc,
                         const int* __restrict__ offs, int* __restrict__ rp,
                         int* __restrict__ cur) {
  int t = threadIdx.x, c = blockIdx.x;
  int i = c * 1024 + t;
  if (i < NN) {
    int r = inc[i] - hist[i] + offs[c];
    rp[i] = r;
    cur[i] = r;
  }
  if (i == 0) rp[NN] = ET;
}

__global__ void k_scatter(const int* __restrict__ edge, int* __restrict__ cur,
                          int* __restrict__ ssrc) {
  int e = blockIdx.x * 256 + threadIdx.x;
  if (e >= ET) return;
  int s, d;
  if (e < EE) { s = edge[e]; d = edge[EE + e]; } else { s = e - EE; d = s; }
  int pos = atomicAdd(&cur[d], 1);
  ssrc[pos] = s;
}

// ---------------- layer-1 aggregation ----------------
// Phase A (lane=edge): exp-weights to LDS. Phase B (lane=(edge-subgroup, f-slice)):
// 4 edges x 64 features per iteration -> 4x shorter latency chain, float4 gathers.
__global__ __launch_bounds__(256) void k_aggB1(
    const float* __restrict__ h1, const float* __restrict__ as1,
    const float* __restrict__ ad1, const float* __restrict__ b1,
    const int* __restrict__ rp, const int* __restrict__ ssrc,
    const float* __restrict__ ws2, const float* __restrict__ wd2,
    float* __restrict__ helu, float* __restrict__ as2, float* __restrict__ ad2) {
  __shared__ float lds_p[4][512];
  __shared__ int   lds_s[4][64];
  __shared__ float lds_v[4][64];
  const int lane = threadIdx.x & 63;
  const int wv = threadIdx.x >> 6;
  const int d = blockIdx.x * 4 + wv;
  if (d >= NN) return;
  const int hl = lane >> 3;        // head for feature=lane (epilogue)
  const int eg = lane >> 4;        // edge subgroup 0..3 (phase B)
  const int fl = lane & 15;        // feature slice (phase B)
  const int hf = fl >> 1;          // head of my 4-feature slice
  float4 a0 = ((const float4*)ad1)[d * 2];
  float4 a1 = ((const float4*)ad1)[d * 2 + 1];
  const float adv[8] = {a0.x, a0.y, a0.z, a0.w, a1.x, a1.y, a1.z, a1.w};
  const int r0 = rp[d], r1 = rp[d + 1];
  float l[8];
#pragma unroll
  for (int h = 0; h < 8; h++) l[h] = 0.f;
  float4 acc = make_float4(0.f, 0.f, 0.f, 0.f);
  for (int base = r0; base < r1; base += 64) {
    int idx = base + lane;
    float p[8];
    int s = 0;
    if (idx < r1) {
      s = ssrc[idx];
      float4 s0 = ((const float4*)as1)[s * 2];
      float4 s1 = ((const float4*)as1)[s * 2 + 1];
      float ev[8] = {s0.x + adv[0], s0.y + adv[1], s0.z + adv[2], s0.w + adv[3],
                     s1.x + adv[4], s1.y + adv[5], s1.z + adv[6], s1.w + adv[7]};
#pragma unroll
      for (int h = 0; h < 8; h++) {
        float e = ev[h];
        e = e > 0.f ? e : NEG * e;
        p[h] = __expf(e);
        l[h] += p[h];
      }
    } else {
#pragma unroll
      for (int h = 0; h < 8; h++) p[h] = 0.f;
    }
    lds_s[wv][lane] = s;
    *((float4*)&lds_p[wv][lane * 8]) = make_float4(p[0], p[1], p[2], p[3]);
    *((float4*)&lds_p[wv][lane * 8 + 4]) = make_float4(p[4], p[5], p[6], p[7]);
    int nc = (min(64, r1 - base) + 3) >> 2;
#pragma unroll 4
    for (int j = 0; j < nc; j++) {
      int e = j * 4 + eg;
      int sj = lds_s[wv][e];
      float w = lds_p[wv][e * 8 + hf];
      float4 g = *((const float4*)&h1[(size_t)sj * 64 + fl * 4]);
      acc.x += w * g.x; acc.y += w * g.y; acc.z += w * g.z; acc.w += w * g.w;
    }
  }
  // reduce across the 4 edge subgroups (bits 4,5 of lane)
#pragma unroll
  for (int off = 16; off <= 32; off <<= 1) {
    acc.x += __shfl_xor(acc.x, off, 64);
    acc.y += __shfl_xor(acc.y, off, 64);
    acc.z += __shfl_xor(acc.z, off, 64);
    acc.w += __shfl_xor(acc.w, off, 64);
  }
  // transpose back to feature-per-lane via per-wave LDS
  if (lane < 16) *((float4*)&lds_v[wv][lane * 4]) = acc;
  float accs = lds_v[wv][lane];
  // denominators
#pragma unroll
  for (int h = 0; h < 8; h++) {
#pragma unroll
    for (int off = 32; off; off >>= 1) l[h] += __shfl_xor(l[h], off, 64);
  }
  float lv = l[0];
  lv = (hl == 1) ? l[1] : lv;
  lv = (hl == 2) ? l[2] : lv;
  lv = (hl == 3) ? l[3] : lv;
  lv = (hl == 4) ? l[4] : lv;
  lv = (hl == 5) ? l[5] : lv;
  lv = (hl == 6) ? l[6] : lv;
  lv = (hl == 7) ? l[7] : lv;
  float val = accs / lv + b1[lane];
  val = val > 0.f ? val : __expf(val) - 1.f;  // ELU
  helu[(size_t)d * 64 + lane] = val;
#pragma unroll
  for (int h = 0; h < 8; h++) {
    float ps = val * ws2[lane * 8 + h];
    float pd = val * wd2[lane * 8 + h];
#pragma unroll
    for (int off = 32; off; off >>= 1) {
      ps += __shfl_xor(ps, off, 64);
      pd += __shfl_xor(pd, off, 64);
    }
    if (lane == 0) {
      as2[d * 8 + h] = ps;
      ad2[d * 8 + h] = pd;
    }
  }
}

// ---------------- layer-2 aggregation in 64-dim space (deferred matmul) ----------------
__global__ __launch_bounds__(256) void k_aggB2(
    const float* __restrict__ helu, const float* __restrict__ as2,
    const float* __restrict__ ad2, const int* __restrict__ rp,
    const int* __restrict__ ssrc, float* __restrict__ agg) {
  __shared__ float lds_p[4][512];
  __shared__ int   lds_s[4][64];
  const int lane = threadIdx.x & 63;
  const int wv = threadIdx.x >> 6;
  const int d = blockIdx.x * 4 + wv;
  if (d >= NN) return;
  const int eg = lane >> 4;
  const int fl = lane & 15;
  float4 a0 = ((const float4*)ad2)[d * 2];
  float4 a1 = ((const float4*)ad2)[d * 2 + 1];
  const float adv[8] = {a0.x, a0.y, a0.z, a0.w, a1.x, a1.y, a1.z, a1.w};
  const int r0 = rp[d], r1 = rp[d + 1];
  float l[8];
  float4 acc[8];
#pragma unroll
  for (int h = 0; h < 8; h++) { l[h] = 0.f; acc[h] = make_float4(0.f, 0.f, 0.f, 0.f); }
  for (int base = r0; base < r1; base += 64) {
    int idx = base + lane;
    float p[8];
    int s = 0;
    if (idx < r1) {
      s = ssrc[idx];
      float4 s0 = ((const float4*)as2)[s * 2];
      float4 s1 = ((const float4*)as2)[s * 2 + 1];
      float ev[8] = {s0.x + adv[0], s0.y + adv[1], s0.z + adv[2], s0.w + adv[3],
                     s1.x + adv[4], s1.y + adv[5], s1.z + adv[6], s1.w + adv[7]};
#pragma unroll
      for (int h = 0; h < 8; h++) {
        float e = ev[h];
        e = e > 0.f ? e : NEG * e;
        p[h] = __expf(e);
        l[h] += p[h];
      }
    } else {
#pragma unroll
      for (int h = 0; h < 8; h++) p[h] = 0.f;
    }
    lds_s[wv][lane] = s;
    *((float4*)&lds_p[wv][lane * 8]) = make_float4(p[0], p[1], p[2], p[3]);
    *((float4*)&lds_p[wv][lane * 8 + 4]) = make_float4(p[4], p[5], p[6], p[7]);
    int nc = (min(64, r1 - base) + 3) >> 2;
#pragma unroll 2
    for (int j = 0; j < nc; j++) {
      int e = j * 4 + eg;
      int sj = lds_s[wv][e];
      float4 g = *((const float4*)&helu[(size_t)sj * 64 + fl * 4]);
      float4 w0 = *((const float4*)&lds_p[wv][e * 8]);
      float4 w1 = *((const float4*)&lds_p[wv][e * 8 + 4]);
      acc[0].x += w0.x * g.x; acc[0].y += w0.x * g.y; acc[0].z += w0.x * g.z; acc[0].w += w0.x * g.w;
      acc[1].x += w0.y * g.x; acc[1].y += w0.y * g.y; acc[1].z += w0.y * g.z; acc[1].w += w0.y * g.w;
      acc[2].x += w0.z * g.x; acc[2].y += w0.z * g.y; acc[2].z += w0.z * g.z; acc[2].w += w0.z * g.w;
      acc[3].x += w0.w * g.x; acc[3].y += w0.w * g.y; acc[3].z += w0.w * g.z; acc[3].w += w0.w * g.w;
      acc[4].x += w1.x * g.x; acc[4].y += w1.x * g.y; acc[4].z += w1.x * g.z; acc[4].w += w1.x * g.w;
      acc[5].x += w1.y * g.x; acc[5].y += w1.y * g.y; acc[5].z += w1.y * g.z; acc[5].w += w1.y * g.w;
      acc[6].x += w1.z * g.x; acc[6].y += w1.z * g.y; acc[6].z += w1.z * g.z; acc[6].w += w1.z * g.w;
      acc[7].x += w1.w * g.x; acc[7].y += w1.w * g.y; acc[7].z += w1.w * g.z; acc[7].w += w1.w * g.w;
    }
  }
#pragma unroll
  for (int h = 0; h < 8; h++) {
#pragma unroll
    for (int off = 16; off <= 32; off <<= 1) {
      acc[h].x += __shfl_xor(acc[h].x, off, 64);
      acc[h].y += __shfl_xor(acc[h].y, off, 64);
      acc[h].z += __shfl_xor(acc[h].z, off, 64);
      acc[h].w += __shfl_xor(acc[h].w, off, 64);
    }
  }
#pragma unroll
  for (int h = 0; h < 8; h++) {
#pragma unroll
    for (int off = 32; off; off >>= 1) l[h] += __shfl_xor(l[h], off, 64);
  }
  if (lane < 16) {
#pragma unroll
    for (int h = 0; h < 8; h++) {
      float rl = 1.0f / l[h];
      ((float4*)agg)[(size_t)d * 128 + h * 16 + fl] =
          make_float4(acc[h].x * rl, acc[h].y * rl, acc[h].z * rl, acc[h].w * rl);
    }
  }
}

// ---------------- GEMM2: out = (1/8)*agg[N,512] @ W2'[512,64] + b2 ----------------
__global__ __launch_bounds__(128) void k_gemm2(const float* __restrict__ agg,
                                               const float* __restrict__ W2,
                                               const float* __restrict__ b2,
                                               float* __restrict__ out) {
  __shared__ float xs[128 * 36];
  __shared__ float wsh[32 * 64];
  const int t = threadIdx.x;
  const int lane = t & 63;
  const int wv = t >> 6;
  const int lr = lane >> 3;
  const int lc = lane & 7;
  const int row0 = blockIdx.x * 128;
  float acc[8][8];
#pragma unroll
  for (int i = 0; i < 8; i++)
#pragma unroll
    for (int j = 0; j < 8; j++) acc[i][j] = 0.f;

  for (int kt = 0; kt < 16; kt++) {
#pragma unroll
    for (int i = 0; i < 8; i++) {            // stage agg tile 128x32
      int s = i * 128 + t;
      int row = s >> 3, c4 = s & 7;
      float4 v = make_float4(0.f, 0.f, 0.f, 0.f);
      if (row0 + row < NN) v = ((const float4*)agg)[(size_t)(row0 + row) * 128 + kt * 8 + c4];
      *((float4*)&xs[row * 36 + c4 * 4]) = v;
    }
#pragma unroll
    for (int i = 0; i < 4; i++) {            // stage W2 sub-block 32x64
      int s = i * 128 + t;
      int k = s >> 4, c4 = s & 15;
      float4 v = ((const float4*)W2)[(size_t)((kt & 1) * 32 + k) * 128 + (kt >> 1) * 16 + c4];
      *((float4*)&wsh[k * 64 + c4 * 4]) = v;
    }
    __syncthreads();
#pragma unroll
    for (int k4 = 0; k4 < 8; k4++) {
      float4 a[8];
#pragma unroll
      for (int i = 0; i < 8; i++)
        a[i] = *((const float4*)&xs[(wv * 64 + lr + 8 * i) * 36 + k4 * 4]);
#pragma unroll
      for (int kk = 0; kk < 4; kk++) {
        float4 bl = *((const float4*)&wsh[(k4 * 4 + kk) * 64 + lc * 8]);
        float4 bh = *((const float4*)&wsh[(k4 * 4 + kk) * 64 + lc * 8 + 4]);
#pragma unroll
        for (int i = 0; i < 8; i++) {
          float av = ((const float*)&a[i])[kk];
          acc[i][0] += av * bl.x; acc[i][1] += av * bl.y;
          acc[i][2] += av * bl.z; acc[i][3] += av * bl.w;
          acc[i][4] += av * bh.x; acc[i][5] += av * bh.y;
          acc[i][6] += av * bh.z; acc[i][7] += av * bh.w;
        }
      }
    }
    __syncthreads();
  }
  float4 b2l = ((const float4*)b2)[lc * 2];
  float4 b2h = ((const float4*)b2)[lc * 2 + 1];
#pragma unroll
  for (int i = 0; i < 8; i++) {
    int row = row0 + wv * 64 + lr + 8 * i;
    if (row >= NN) continue;
    ((float4*)out)[(size_t)row * 16 + lc * 2] =
        make_float4(0.125f * acc[i][0] + b2l.x, 0.125f * acc[i][1] + b2l.y,
                    0.125f * acc[i][2] + b2l.z, 0.125f * acc[i][3] + b2l.w);
    ((float4*)out)[(size_t)row * 16 + lc * 2 + 1] =
        make_float4(0.125f * acc[i][4] + b2h.x, 0.125f * acc[i][5] + b2h.y,
                    0.125f * acc[i][6] + b2h.z, 0.125f * acc[i][7] + b2h.w);
  }
}

extern "C" void kernel_launch(void* const* d_in, const int* in_sizes, int n_in,
                              void* d_out, int out_size, void* d_ws, size_t ws_size,
                              hipStream_t stream) {
  const float* x      = (const float*)d_in[0];
  const float* W1     = (const float*)d_in[1];
  const float* a_src1 = (const float*)d_in[2];
  const float* a_dst1 = (const float*)d_in[3];
  const float* b1     = (const float*)d_in[4];
  const float* W2     = (const float*)d_in[5];
  const float* a_src2 = (const float*)d_in[6];
  const float* a_dst2 = (const float*)d_in[7];
  const float* b2     = (const float*)d_in[8];
  const int*   edge   = (const int*)d_in[9];

  char* ws = (char*)d_ws;
  float* h1   = (float*)(ws + OFF_H1);
  float* helu = (float*)(ws + OFF_HELU);
  float* as1  = (float*)(ws + OFF_AS1);
  float* ad1  = (float*)(ws + OFF_AD1);
  float* as2  = (float*)(ws + OFF_AS2);
  float* ad2  = (float*)(ws + OFF_AD2);
  float* ws2  = (float*)(ws + OFF_WS2);
  float* wd2  = (float*)(ws + OFF_WD2);
  int* hist   = (int*)(ws + OFF_HIST);
  int* inc    = (int*)(ws + OFF_INC);
  int* part   = (int*)(ws + OFF_PART);
  int* offs   = (int*)(ws + OFF_OFFS);
  int* rp     = (int*)(ws + OFF_RP);
  int* cur    = (int*)(ws + OFF_CUR);
  int* ssrc   = (int*)(ws + OFF_SRC);
  float* agg  = (float*)(ws + OFF_AGG);
  float* out  = (float*)d_out;

  hipMemsetAsync(hist, 0, (size_t)NN * 4, stream);

  k_gemm1<<<(NN + 127) / 128, 128, 0, stream>>>(x, W1, a_src1, a_dst1, h1, as1, ad1);
  k_w2proj<<<1, 512, 0, stream>>>(W2, a_src2, a_dst2, ws2, wd2);
  k_hist<<<(ET + 255) / 256, 256, 0, stream>>>(edge, hist);
  k_scan_a<<<NCH, 1024, 0, stream>>>(hist, inc, part);
  k_scan_b<<<1, 128, 0, stream>>>(part, offs);
  k_scan_c<<<NCH, 1024, 0, stream>>>(hist, inc, offs, rp, cur);
  k_scatter<<<(ET + 255) / 256, 256, 0, stream>>>(edge, cur, ssrc);
  k_aggB1<<<(NN + 3) / 4, 256, 0, stream>>>(h1, as1, ad1, b1, rp, ssrc, ws2, wd2, helu, as2, ad2);
  k_aggB2<<<(NN + 3) / 4, 256, 0, stream>>>(helu, as2, ad2, rp, ssrc, agg);
  k_gemm2<<<(NN + 127) / 128, 128, 0, stream>>>(agg, W2, b2, out);
}

// Round 5
// 794.100 us; speedup vs baseline: 1.8084x; 1.3063x over previous
//
#include <hip/hip_runtime.h>
#include <hip/hip_fp16.h>
#include <math.h>

#define NN 100000
#define EE 1600000
#define ET 1700000   // EE + NN self loops
#define NEG 0.2f
#define NCH 98       // ceil(NN/1024)

// ---------------- ws layout (bytes) ----------------
static constexpr size_t alignup(size_t x) { return (x + 255) & ~(size_t)255; }
static constexpr size_t OFF_H1H  = 0;                                    // N*64 fp16
static constexpr size_t OFF_HELU = alignup(OFF_H1H  + (size_t)NN*64*2);  // N*64 fp16
static constexpr size_t OFF_AS1H = alignup(OFF_HELU + (size_t)NN*64*2);  // N*8 fp16
static constexpr size_t OFF_AD1  = alignup(OFF_AS1H + (size_t)NN*8*2);   // N*8 f32
static constexpr size_t OFF_AS2H = alignup(OFF_AD1  + (size_t)NN*8*4);   // N*8 fp16
static constexpr size_t OFF_AD2  = alignup(OFF_AS2H + (size_t)NN*8*2);   // N*8 f32
static constexpr size_t OFF_WSD2 = alignup(OFF_AD2  + (size_t)NN*8*4);   // 64*16 f32
static constexpr size_t OFF_HIST = alignup(OFF_WSD2 + 64*16*4);          // N int
static constexpr size_t OFF_INC  = alignup(OFF_HIST + (size_t)NN*4);
static constexpr size_t OFF_PART = alignup(OFF_INC  + (size_t)NN*4);
static constexpr size_t OFF_OFFS = alignup(OFF_PART + 128*4);
static constexpr size_t OFF_RP   = alignup(OFF_OFFS + 128*4);
static constexpr size_t OFF_CUR  = alignup(OFF_RP   + (size_t)(NN+1)*4);
static constexpr size_t OFF_SRC  = alignup(OFF_CUR  + (size_t)NN*4);     // ET int
static constexpr size_t OFF_AGGH = alignup(OFF_SRC  + (size_t)ET*4);     // N*512 fp16

__device__ inline void unpack8(float4 raw, float* g) {
  __half2* hp = (__half2*)&raw;
  float2 a = __half22float2(hp[0]); g[0] = a.x; g[1] = a.y;
  float2 b = __half22float2(hp[1]); g[2] = b.x; g[3] = b.y;
  float2 c = __half22float2(hp[2]); g[4] = c.x; g[5] = c.y;
  float2 d = __half22float2(hp[3]); g[6] = d.x; g[7] = d.y;
}

// ---------------- GEMM1: h1h = fp16(x[N,256] @ W1[256,64]), fused as1/ad1 ----
__global__ __launch_bounds__(128) void k_gemm1(const float* __restrict__ x,
                                               const float* __restrict__ W1,
                                               const float* __restrict__ a_src1,
                                               const float* __restrict__ a_dst1,
                                               __half* __restrict__ h1h,
                                               __half* __restrict__ as1h,
                                               float* __restrict__ ad1) {
  __shared__ float xs[128 * 36];
  __shared__ float wsh[32 * 64];
  const int t = threadIdx.x;
  const int lane = t & 63;
  const int wv = t >> 6;
  const int lr = lane >> 3;
  const int lc = lane & 7;
  const int row0 = blockIdx.x * 128;
  float acc[8][8];
#pragma unroll
  for (int i = 0; i < 8; i++)
#pragma unroll
    for (int j = 0; j < 8; j++) acc[i][j] = 0.f;

  for (int kt = 0; kt < 8; kt++) {
#pragma unroll
    for (int i = 0; i < 8; i++) {
      int s = i * 128 + t;
      int row = s >> 3, c4 = s & 7;
      float4 v = make_float4(0.f, 0.f, 0.f, 0.f);
      if (row0 + row < NN) v = ((const float4*)x)[(size_t)(row0 + row) * 64 + kt * 8 + c4];
      *((float4*)&xs[row * 36 + c4 * 4]) = v;
    }
#pragma unroll
    for (int i = 0; i < 4; i++) {
      int s = i * 128 + t;
      int k = s >> 4, c4 = s & 15;
      float4 v = ((const float4*)W1)[(kt * 32 + k) * 16 + c4];
      *((float4*)&wsh[k * 64 + c4 * 4]) = v;
    }
    __syncthreads();
#pragma unroll
    for (int k4 = 0; k4 < 8; k4++) {
      float4 a[8];
#pragma unroll
      for (int i = 0; i < 8; i++)
        a[i] = *((const float4*)&xs[(wv * 64 + lr + 8 * i) * 36 + k4 * 4]);
#pragma unroll
      for (int kk = 0; kk < 4; kk++) {
        float4 bl = *((const float4*)&wsh[(k4 * 4 + kk) * 64 + lc * 8]);
        float4 bh = *((const float4*)&wsh[(k4 * 4 + kk) * 64 + lc * 8 + 4]);
#pragma unroll
        for (int i = 0; i < 8; i++) {
          float av = ((const float*)&a[i])[kk];
          acc[i][0] += av * bl.x; acc[i][1] += av * bl.y;
          acc[i][2] += av * bl.z; acc[i][3] += av * bl.w;
          acc[i][4] += av * bh.x; acc[i][5] += av * bh.y;
          acc[i][6] += av * bh.z; acc[i][7] += av * bh.w;
        }
      }
    }
    __syncthreads();
  }
  float4 s0 = ((const float4*)a_src1)[lc * 2];
  float4 s1 = ((const float4*)a_src1)[lc * 2 + 1];
  float4 d0 = ((const float4*)a_dst1)[lc * 2];
  float4 d1 = ((const float4*)a_dst1)[lc * 2 + 1];
#pragma unroll
  for (int i = 0; i < 8; i++) {
    int row = row0 + wv * 64 + lr + 8 * i;
    if (row >= NN) continue;
    union { __half2 h2[4]; float4 f4; } u;
    u.h2[0] = __floats2half2_rn(acc[i][0], acc[i][1]);
    u.h2[1] = __floats2half2_rn(acc[i][2], acc[i][3]);
    u.h2[2] = __floats2half2_rn(acc[i][4], acc[i][5]);
    u.h2[3] = __floats2half2_rn(acc[i][6], acc[i][7]);
    *((float4*)&h1h[(size_t)row * 64 + lc * 8]) = u.f4;
    float sd = acc[i][0] * s0.x + acc[i][1] * s0.y + acc[i][2] * s0.z + acc[i][3] * s0.w
             + acc[i][4] * s1.x + acc[i][5] * s1.y + acc[i][6] * s1.z + acc[i][7] * s1.w;
    float dd = acc[i][0] * d0.x + acc[i][1] * d0.y + acc[i][2] * d0.z + acc[i][3] * d0.w
             + acc[i][4] * d1.x + acc[i][5] * d1.y + acc[i][6] * d1.z + acc[i][7] * d1.w;
    as1h[row * 8 + lc] = __float2half(sd);
    ad1[row * 8 + lc] = dd;
  }
}

// ---------------- wsd2[k*16+j]: j<8 -> W2-proj of a_src2, else a_dst2 --------
__global__ void k_w2proj(const float* __restrict__ W2, const float* __restrict__ a_src2,
                         const float* __restrict__ a_dst2, float* __restrict__ wsd2) {
  int t = threadIdx.x;  // 1024 threads: t = k*16+j
  int k = t >> 4, j = t & 15, h = j & 7;
  const float* av = (j < 8) ? a_src2 : a_dst2;
  float s = 0.f;
  for (int f = 0; f < 64; f++) s += W2[k * 512 + h * 64 + f] * av[h * 64 + f];
  wsd2[t] = s;
}

// ---------------- counting sort by dst ----------------
__global__ void k_hist(const int* __restrict__ edge, int* __restrict__ hist) {
  int e = blockIdx.x * 256 + threadIdx.x;
  if (e >= ET) return;
  int d = (e < EE) ? edge[EE + e] : (e - EE);
  atomicAdd(&hist[d], 1);
}

__global__ void k_scan_a(const int* __restrict__ hist, int* __restrict__ inc,
                         int* __restrict__ part) {
  __shared__ int sm[1024];
  int t = threadIdx.x, c = blockIdx.x;
  int i = c * 1024 + t;
  int v = (i < NN) ? hist[i] : 0;
  sm[t] = v;
  for (int off = 1; off < 1024; off <<= 1) {
    __syncthreads();
    int a = (t >= off) ? sm[t - off] : 0;
    __syncthreads();
    sm[t] += a;
  }
  if (i < NN) inc[i] = sm[t];
  if (t == 1023) part[c] = sm[1023];
}

__global__ void k_scan_b(const int* __restrict__ part, int* __restrict__ offs) {
  int t = threadIdx.x;
  if (t >= 128) return;
  int run = 0;
  for (int c = 0; c < NCH; c++)
    if (c < t) run += part[c];
  if (t < NCH) offs[t] = run;
}

__global__ void k_scan_c(const int* __restrict__ hist, const int* __restrict__ inc,
                         const int* __restrict__ offs, int* __restrict__ rp,
                         int* __restrict__ cur) {
  int t = threadIdx.x, c = blockIdx.x;
  int i = c * 1024 + t;
  if (i < NN) {
    int r = inc[i] - hist[i] + offs[c];
    rp[i] = r;
    cur[i] = r;
  }
  if (i == 0) rp[NN] = ET;
}

__global__ void k_scatter(const int* __restrict__ edge, int* __restrict__ cur,
                          int* __restrict__ ssrc) {
  int e = blockIdx.x * 256 + threadIdx.x;
  if (e >= ET) return;
  int s, d;
  if (e < EE) { s = edge[e]; d = edge[EE + e]; } else { s = e - EE; d = s; }
  int pos = atomicAdd(&cur[d], 1);
  ssrc[pos] = s;
}

// ---------------- layer-1 aggregation (fp16 gathers, 8 edges/instr) ---------
__global__ __launch_bounds__(256) void k_aggB1(
    const __half* __restrict__ h1h, const __half* __restrict__ as1h,
    const float* __restrict__ ad1, const float* __restrict__ b1,
    const int* __restrict__ rp, const int* __restrict__ ssrc,
    const float* __restrict__ wsd2,
    __half* __restrict__ heluh, __half* __restrict__ as2h, float* __restrict__ ad2) {
  __shared__ float lds_p[4][512];
  __shared__ int   lds_s[4][64];
  __shared__ float lds_v[4][64];
  const int lane = threadIdx.x & 63;
  const int wv = threadIdx.x >> 6;
  const int d = blockIdx.x * 4 + wv;
  if (d >= NN) return;
  const int eg = lane >> 3;        // edge subgroup 0..7
  const int fl = lane & 7;         // 8-feature slice == head (phase B)
  float4 a0 = ((const float4*)ad1)[d * 2];
  float4 a1 = ((const float4*)ad1)[d * 2 + 1];
  const float adv[8] = {a0.x, a0.y, a0.z, a0.w, a1.x, a1.y, a1.z, a1.w};
  const int r0 = rp[d], r1 = rp[d + 1];
  float acc[8];
#pragma unroll
  for (int k = 0; k < 8; k++) acc[k] = 0.f;
  float lsum = 0.f;
  for (int base = r0; base < r1; base += 64) {
    int idx = base + lane;
    float p[8];
    int s = 0;
    if (idx < r1) {
      s = ssrc[idx];
      float4 raw = *((const float4*)&as1h[s * 8]);
      float ev[8];
      unpack8(raw, ev);
#pragma unroll
      for (int h = 0; h < 8; h++) {
        float e = ev[h] + adv[h];
        e = e > 0.f ? e : NEG * e;
        p[h] = __expf(e);
      }
    } else {
#pragma unroll
      for (int h = 0; h < 8; h++) p[h] = 0.f;
    }
    lds_s[wv][lane] = s;
    *((float4*)&lds_p[wv][lane * 8]) = make_float4(p[0], p[1], p[2], p[3]);
    *((float4*)&lds_p[wv][lane * 8 + 4]) = make_float4(p[4], p[5], p[6], p[7]);
    int nc = (min(64, r1 - base) + 7) >> 3;
#pragma unroll 2
    for (int j = 0; j < nc; j++) {
      int e = j * 8 + eg;
      int sj = lds_s[wv][e];
      float w = lds_p[wv][e * 8 + fl];
      float4 raw = *((const float4*)&h1h[(size_t)sj * 64 + fl * 8]);
      float g[8];
      unpack8(raw, g);
      lsum += w;
#pragma unroll
      for (int k = 0; k < 8; k++) acc[k] += w * g[k];
    }
  }
  // reduce across 8 edge subgroups (lane bits 3,4,5)
#pragma unroll
  for (int off = 8; off <= 32; off <<= 1) {
#pragma unroll
    for (int k = 0; k < 8; k++) acc[k] += __shfl_xor(acc[k], off, 64);
    lsum += __shfl_xor(lsum, off, 64);
  }
  if (lane < 8) {
#pragma unroll
    for (int k = 0; k < 8; k++) lds_v[wv][lane * 8 + k] = acc[k];
    lds_p[wv][lane] = lsum;   // l[head=lane]
  }
  float accs = lds_v[wv][lane];
  float lv = lds_p[wv][lane >> 3];
  float val = accs / lv + b1[lane];
  val = val > 0.f ? val : __expf(val) - 1.f;  // ELU
  heluh[(size_t)d * 64 + lane] = __float2half(val);
  // layer-2 logits: 4 groups of 16 features x 16 outputs (8 src + 8 dst)
  lds_v[wv][lane] = val;
  int g = lane >> 4, j = lane & 15;
  float dot = 0.f;
#pragma unroll
  for (int f = 0; f < 16; f++) dot += lds_v[wv][g * 16 + f] * wsd2[(g * 16 + f) * 16 + j];
  dot += __shfl_xor(dot, 16, 64);
  dot += __shfl_xor(dot, 32, 64);
  if (lane < 16) {
    if (j < 8) as2h[d * 8 + j] = __float2half(dot);
    else       ad2[d * 8 + (j & 7)] = dot;
  }
}

// ---------------- layer-2 aggregation in 64-dim space (fp16, deferred matmul) --
__global__ __launch_bounds__(256) void k_aggB2(
    const __half* __restrict__ heluh, const __half* __restrict__ as2h,
    const float* __restrict__ ad2, const int* __restrict__ rp,
    const int* __restrict__ ssrc, __half* __restrict__ aggh) {
  __shared__ float lds_p[4][512];
  __shared__ int   lds_s[4][64];
  const int lane = threadIdx.x & 63;
  const int wv = threadIdx.x >> 6;
  const int d = blockIdx.x * 4 + wv;
  if (d >= NN) return;
  const int eg = lane >> 4;        // edge subgroup 0..3
  const int fl = lane & 15;        // 4-feature slice
  float4 a0 = ((const float4*)ad2)[d * 2];
  float4 a1 = ((const float4*)ad2)[d * 2 + 1];
  const float adv[8] = {a0.x, a0.y, a0.z, a0.w, a1.x, a1.y, a1.z, a1.w};
  const int r0 = rp[d], r1 = rp[d + 1];
  float l8[8];
  float acc[8][4];
#pragma unroll
  for (int h = 0; h < 8; h++) {
    l8[h] = 0.f;
#pragma unroll
    for (int k = 0; k < 4; k++) acc[h][k] = 0.f;
  }
  for (int base = r0; base < r1; base += 64) {
    int idx = base + lane;
    float p[8];
    int s = 0;
    if (idx < r1) {
      s = ssrc[idx];
      float4 raw = *((const float4*)&as2h[s * 8]);
      float ev[8];
      unpack8(raw, ev);
#pragma unroll
      for (int h = 0; h < 8; h++) {
        float e = ev[h] + adv[h];
        e = e > 0.f ? e : NEG * e;
        p[h] = __expf(e);
      }
    } else {
#pragma unroll
      for (int h = 0; h < 8; h++) p[h] = 0.f;
    }
    lds_s[wv][lane] = s;
    *((float4*)&lds_p[wv][lane * 8]) = make_float4(p[0], p[1], p[2], p[3]);
    *((float4*)&lds_p[wv][lane * 8 + 4]) = make_float4(p[4], p[5], p[6], p[7]);
    int nc = (min(64, r1 - base) + 3) >> 2;
#pragma unroll 2
    for (int j = 0; j < nc; j++) {
      int e = j * 4 + eg;
      int sj = lds_s[wv][e];
      float2 raw = *((const float2*)&heluh[(size_t)sj * 64 + fl * 4]);
      __half2* hp = (__half2*)&raw;
      float2 ga = __half22float2(hp[0]);
      float2 gb = __half22float2(hp[1]);
      float g[4] = {ga.x, ga.y, gb.x, gb.y};
      float4 w0 = *((const float4*)&lds_p[wv][e * 8]);
      float4 w1 = *((const float4*)&lds_p[wv][e * 8 + 4]);
      float w[8] = {w0.x, w0.y, w0.z, w0.w, w1.x, w1.y, w1.z, w1.w};
#pragma unroll
      for (int h = 0; h < 8; h++) {
        l8[h] += w[h];
#pragma unroll
        for (int k = 0; k < 4; k++) acc[h][k] += w[h] * g[k];
      }
    }
  }
  // reduce across 4 edge subgroups (lane bits 4,5)
#pragma unroll
  for (int off = 16; off <= 32; off <<= 1) {
#pragma unroll
    for (int h = 0; h < 8; h++) {
      l8[h] += __shfl_xor(l8[h], off, 64);
#pragma unroll
      for (int k = 0; k < 4; k++) acc[h][k] += __shfl_xor(acc[h][k], off, 64);
    }
  }
  if (lane < 16) {
#pragma unroll
    for (int h = 0; h < 8; h++) {
      float rl = 1.0f / l8[h];
      union { __half2 h2[2]; float2 f2; } u;
      u.h2[0] = __floats2half2_rn(acc[h][0] * rl, acc[h][1] * rl);
      u.h2[1] = __floats2half2_rn(acc[h][2] * rl, acc[h][3] * rl);
      *((float2*)&aggh[(size_t)d * 512 + h * 64 + fl * 4]) = u.f2;
    }
  }
}

// ---------------- GEMM2: out = (1/8)*aggh[N,512] @ W2'[512,64] + b2 ----------
__global__ __launch_bounds__(128) void k_gemm2(const __half* __restrict__ aggh,
                                               const float* __restrict__ W2,
                                               const float* __restrict__ b2,
                                               float* __restrict__ out) {
  __shared__ float xs[128 * 36];
  __shared__ float wsh[32 * 64];
  const int t = threadIdx.x;
  const int lane = t & 63;
  const int wv = t >> 6;
  const int lr = lane >> 3;
  const int lc = lane & 7;
  const int row0 = blockIdx.x * 128;
  float acc[8][8];
#pragma unroll
  for (int i = 0; i < 8; i++)
#pragma unroll
    for (int j = 0; j < 8; j++) acc[i][j] = 0.f;

  for (int kt = 0; kt < 16; kt++) {
#pragma unroll
    for (int i = 0; i < 4; i++) {            // stage aggh tile 128x32 (fp16->f32)
      int s = i * 128 + t;
      int row = s >> 2, c8 = s & 3;
      float4 raw = make_float4(0.f, 0.f, 0.f, 0.f);
      if (row0 + row < NN) raw = *((const float4*)&aggh[(size_t)(row0 + row) * 512 + kt * 32 + c8 * 8]);
      float g[8];
      unpack8(raw, g);
      *((float4*)&xs[row * 36 + c8 * 8])     = make_float4(g[0], g[1], g[2], g[3]);
      *((float4*)&xs[row * 36 + c8 * 8 + 4]) = make_float4(g[4], g[5], g[6], g[7]);
    }
#pragma unroll
    for (int i = 0; i < 4; i++) {            // stage W2 sub-block 32x64
      int s = i * 128 + t;
      int k = s >> 4, c4 = s & 15;
      float4 v = ((const float4*)W2)[(size_t)((kt & 1) * 32 + k) * 128 + (kt >> 1) * 16 + c4];
      *((float4*)&wsh[k * 64 + c4 * 4]) = v;
    }
    __syncthreads();
#pragma unroll
    for (int k4 = 0; k4 < 8; k4++) {
      float4 a[8];
#pragma unroll
      for (int i = 0; i < 8; i++)
        a[i] = *((const float4*)&xs[(wv * 64 + lr + 8 * i) * 36 + k4 * 4]);
#pragma unroll
      for (int kk = 0; kk < 4; kk++) {
        float4 bl = *((const float4*)&wsh[(k4 * 4 + kk) * 64 + lc * 8]);
        float4 bh = *((const float4*)&wsh[(k4 * 4 + kk) * 64 + lc * 8 + 4]);
#pragma unroll
        for (int i = 0; i < 8; i++) {
          float av = ((const float*)&a[i])[kk];
          acc[i][0] += av * bl.x; acc[i][1] += av * bl.y;
          acc[i][2] += av * bl.z; acc[i][3] += av * bl.w;
          acc[i][4] += av * bh.x; acc[i][5] += av * bh.y;
          acc[i][6] += av * bh.z; acc[i][7] += av * bh.w;
        }
      }
    }
    __syncthreads();
  }
  float4 b2l = ((const float4*)b2)[lc * 2];
  float4 b2h = ((const float4*)b2)[lc * 2 + 1];
#pragma unroll
  for (int i = 0; i < 8; i++) {
    int row = row0 + wv * 64 + lr + 8 * i;
    if (row >= NN) continue;
    ((float4*)out)[(size_t)row * 16 + lc * 2] =
        make_float4(0.125f * acc[i][0] + b2l.x, 0.125f * acc[i][1] + b2l.y,
                    0.125f * acc[i][2] + b2l.z, 0.125f * acc[i][3] + b2l.w);
    ((float4*)out)[(size_t)row * 16 + lc * 2 + 1] =
        make_float4(0.125f * acc[i][4] + b2h.x, 0.125f * acc[i][5] + b2h.y,
                    0.125f * acc[i][6] + b2h.z, 0.125f * acc[i][7] + b2h.w);
  }
}

extern "C" void kernel_launch(void* const* d_in, const int* in_sizes, int n_in,
                              void* d_out, int out_size, void* d_ws, size_t ws_size,
                              hipStream_t stream) {
  const float* x      = (const float*)d_in[0];
  const float* W1     = (const float*)d_in[1];
  const float* a_src1 = (const float*)d_in[2];
  const float* a_dst1 = (const float*)d_in[3];
  const float* b1     = (const float*)d_in[4];
  const float* W2     = (const float*)d_in[5];
  const float* a_src2 = (const float*)d_in[6];
  const float* a_dst2 = (const float*)d_in[7];
  const float* b2     = (const float*)d_in[8];
  const int*   edge   = (const int*)d_in[9];

  char* ws = (char*)d_ws;
  __half* h1h   = (__half*)(ws + OFF_H1H);
  __half* heluh = (__half*)(ws + OFF_HELU);
  __half* as1h  = (__half*)(ws + OFF_AS1H);
  float*  ad1   = (float*)(ws + OFF_AD1);
  __half* as2h  = (__half*)(ws + OFF_AS2H);
  float*  ad2   = (float*)(ws + OFF_AD2);
  float*  wsd2  = (float*)(ws + OFF_WSD2);
  int* hist   = (int*)(ws + OFF_HIST);
  int* inc    = (int*)(ws + OFF_INC);
  int* part   = (int*)(ws + OFF_PART);
  int* offs   = (int*)(ws + OFF_OFFS);
  int* rp     = (int*)(ws + OFF_RP);
  int* cur    = (int*)(ws + OFF_CUR);
  int* ssrc   = (int*)(ws + OFF_SRC);
  __half* aggh = (__half*)(ws + OFF_AGGH);
  float* out  = (float*)d_out;

  hipMemsetAsync(hist, 0, (size_t)NN * 4, stream);

  k_gemm1<<<(NN + 127) / 128, 128, 0, stream>>>(x, W1, a_src1, a_dst1, h1h, as1h, ad1);
  k_w2proj<<<1, 1024, 0, stream>>>(W2, a_src2, a_dst2, wsd2);
  k_hist<<<(ET + 255) / 256, 256, 0, stream>>>(edge, hist);
  k_scan_a<<<NCH, 1024, 0, stream>>>(hist, inc, part);
  k_scan_b<<<1, 128, 0, stream>>>(part, offs);
  k_scan_c<<<NCH, 1024, 0, stream>>>(hist, inc, offs, rp, cur);
  k_scatter<<<(ET + 255) / 256, 256, 0, stream>>>(edge, cur, ssrc);
  k_aggB1<<<(NN + 3) / 4, 256, 0, stream>>>(h1h, as1h, ad1, b1, rp, ssrc, wsd2, heluh, as2h, ad2);
  k_aggB2<<<(NN + 3) / 4, 256, 0, stream>>>(heluh, as2h, ad2, rp, ssrc, aggh);
  k_gemm2<<<(NN + 127) / 128, 128, 0, stream>>>(aggh, W2, b2, out);
}

// Round 6
// 728.763 us; speedup vs baseline: 1.9705x; 1.0897x over previous
//
#include <hip/hip_runtime.h>
#include <hip/hip_fp16.h>
#include <math.h>

#define NN 100000
#define EE 1600000
#define ET 1700000   // EE + NN self loops
#define NEG 0.2f
#define NCH 98       // ceil(NN/1024)

typedef _Float16 half8_t __attribute__((ext_vector_type(8)));
typedef float f32x4 __attribute__((ext_vector_type(4)));

// ---------------- ws layout (bytes) ----------------
static constexpr size_t alignup(size_t x) { return (x + 255) & ~(size_t)255; }
static constexpr size_t OFF_H1H  = 0;                                    // N*64 fp16
static constexpr size_t OFF_HELU = alignup(OFF_H1H  + (size_t)NN*64*2);  // N*64 fp16
static constexpr size_t OFF_AS1H = alignup(OFF_HELU + (size_t)NN*64*2);  // N*8 fp16
static constexpr size_t OFF_AD1  = alignup(OFF_AS1H + (size_t)NN*8*2);   // N*8 f32
static constexpr size_t OFF_AS2H = alignup(OFF_AD1  + (size_t)NN*8*4);   // N*8 fp16
static constexpr size_t OFF_AD2  = alignup(OFF_AS2H + (size_t)NN*8*2);   // N*8 f32
static constexpr size_t OFF_WSD2 = alignup(OFF_AD2  + (size_t)NN*8*4);   // 64*16 f32
static constexpr size_t OFF_W2T  = alignup(OFF_WSD2 + 64*16*4);          // 64*512 fp16
static constexpr size_t OFF_HIST = alignup(OFF_W2T  + 64*512*2);         // N int
static constexpr size_t OFF_INC  = alignup(OFF_HIST + (size_t)NN*4);
static constexpr size_t OFF_PART = alignup(OFF_INC  + (size_t)NN*4);
static constexpr size_t OFF_OFFS = alignup(OFF_PART + 128*4);
static constexpr size_t OFF_RP   = alignup(OFF_OFFS + 128*4);
static constexpr size_t OFF_CUR  = alignup(OFF_RP   + (size_t)(NN+1)*4);
static constexpr size_t OFF_SRC  = alignup(OFF_CUR  + (size_t)NN*4);     // ET int
static constexpr size_t OFF_AGGH = alignup(OFF_SRC  + (size_t)ET*4);     // N*512 fp16

__device__ inline void unpack8(float4 raw, float* g) {
  __half2* hp = (__half2*)&raw;
  float2 a = __half22float2(hp[0]); g[0] = a.x; g[1] = a.y;
  float2 b = __half22float2(hp[1]); g[2] = b.x; g[3] = b.y;
  float2 c = __half22float2(hp[2]); g[4] = c.x; g[5] = c.y;
  float2 d = __half22float2(hp[3]); g[6] = d.x; g[7] = d.y;
}

// ---------------- GEMM1: h1h = fp16(x[N,256] @ W1[256,64]), fused as1/ad1 ----
__global__ __launch_bounds__(128) void k_gemm1(const float* __restrict__ x,
                                               const float* __restrict__ W1,
                                               const float* __restrict__ a_src1,
                                               const float* __restrict__ a_dst1,
                                               __half* __restrict__ h1h,
                                               __half* __restrict__ as1h,
                                               float* __restrict__ ad1) {
  __shared__ float xs[128 * 36];
  __shared__ float wsh[32 * 64];
  const int t = threadIdx.x;
  const int lane = t & 63;
  const int wv = t >> 6;
  const int lr = lane >> 3;
  const int lc = lane & 7;
  const int row0 = blockIdx.x * 128;
  float acc[8][8];
#pragma unroll
  for (int i = 0; i < 8; i++)
#pragma unroll
    for (int j = 0; j < 8; j++) acc[i][j] = 0.f;

  for (int kt = 0; kt < 8; kt++) {
#pragma unroll
    for (int i = 0; i < 8; i++) {
      int s = i * 128 + t;
      int row = s >> 3, c4 = s & 7;
      float4 v = make_float4(0.f, 0.f, 0.f, 0.f);
      if (row0 + row < NN) v = ((const float4*)x)[(size_t)(row0 + row) * 64 + kt * 8 + c4];
      *((float4*)&xs[row * 36 + c4 * 4]) = v;
    }
#pragma unroll
    for (int i = 0; i < 4; i++) {
      int s = i * 128 + t;
      int k = s >> 4, c4 = s & 15;
      float4 v = ((const float4*)W1)[(kt * 32 + k) * 16 + c4];
      *((float4*)&wsh[k * 64 + c4 * 4]) = v;
    }
    __syncthreads();
#pragma unroll
    for (int k4 = 0; k4 < 8; k4++) {
      float4 a[8];
#pragma unroll
      for (int i = 0; i < 8; i++)
        a[i] = *((const float4*)&xs[(wv * 64 + lr + 8 * i) * 36 + k4 * 4]);
#pragma unroll
      for (int kk = 0; kk < 4; kk++) {
        float4 bl = *((const float4*)&wsh[(k4 * 4 + kk) * 64 + lc * 8]);
        float4 bh = *((const float4*)&wsh[(k4 * 4 + kk) * 64 + lc * 8 + 4]);
#pragma unroll
        for (int i = 0; i < 8; i++) {
          float av = ((const float*)&a[i])[kk];
          acc[i][0] += av * bl.x; acc[i][1] += av * bl.y;
          acc[i][2] += av * bl.z; acc[i][3] += av * bl.w;
          acc[i][4] += av * bh.x; acc[i][5] += av * bh.y;
          acc[i][6] += av * bh.z; acc[i][7] += av * bh.w;
        }
      }
    }
    __syncthreads();
  }
  float4 s0 = ((const float4*)a_src1)[lc * 2];
  float4 s1 = ((const float4*)a_src1)[lc * 2 + 1];
  float4 d0 = ((const float4*)a_dst1)[lc * 2];
  float4 d1 = ((const float4*)a_dst1)[lc * 2 + 1];
#pragma unroll
  for (int i = 0; i < 8; i++) {
    int row = row0 + wv * 64 + lr + 8 * i;
    if (row >= NN) continue;
    union { __half2 h2[4]; float4 f4; } u;
    u.h2[0] = __floats2half2_rn(acc[i][0], acc[i][1]);
    u.h2[1] = __floats2half2_rn(acc[i][2], acc[i][3]);
    u.h2[2] = __floats2half2_rn(acc[i][4], acc[i][5]);
    u.h2[3] = __floats2half2_rn(acc[i][6], acc[i][7]);
    *((float4*)&h1h[(size_t)row * 64 + lc * 8]) = u.f4;
    float sd = acc[i][0] * s0.x + acc[i][1] * s0.y + acc[i][2] * s0.z + acc[i][3] * s0.w
             + acc[i][4] * s1.x + acc[i][5] * s1.y + acc[i][6] * s1.z + acc[i][7] * s1.w;
    float dd = acc[i][0] * d0.x + acc[i][1] * d0.y + acc[i][2] * d0.z + acc[i][3] * d0.w
             + acc[i][4] * d1.x + acc[i][5] * d1.y + acc[i][6] * d1.z + acc[i][7] * d1.w;
    as1h[row * 8 + lc] = __float2half(sd);
    ad1[row * 8 + lc] = dd;
  }
}

// ---------------- wsd2[k*16+j]: j<8 -> W2-proj of a_src2, else a_dst2 --------
__global__ void k_w2proj(const float* __restrict__ W2, const float* __restrict__ a_src2,
                         const float* __restrict__ a_dst2, float* __restrict__ wsd2) {
  int t = threadIdx.x;  // 1024 threads: t = k*16+j
  int k = t >> 4, j = t & 15, h = j & 7;
  const float* av = (j < 8) ? a_src2 : a_dst2;
  float s = 0.f;
  for (int f = 0; f < 64; f++) s += W2[k * 512 + h * 64 + f] * av[h * 64 + f];
  wsd2[t] = s;
}

// ---------------- W2t[f][h*64+kk] = fp16(W2[kk][h*64+f]) : B for MFMA gemm2 --
__global__ void k_w2t(const float* __restrict__ W2, _Float16* __restrict__ W2t) {
  int t = blockIdx.x * 256 + threadIdx.x;  // 32768 = 64*512
  if (t >= 64 * 512) return;
  int f = t >> 9, k = t & 511;
  int h = k >> 6, kk = k & 63;
  W2t[t] = (_Float16)W2[kk * 512 + h * 64 + f];
}

// ---------------- counting sort by dst ----------------
__global__ void k_hist(const int* __restrict__ edge, int* __restrict__ hist) {
  int e = blockIdx.x * 256 + threadIdx.x;
  if (e >= ET) return;
  int d = (e < EE) ? edge[EE + e] : (e - EE);
  atomicAdd(&hist[d], 1);
}

__global__ void k_scan_a(const int* __restrict__ hist, int* __restrict__ inc,
                         int* __restrict__ part) {
  __shared__ int sm[1024];
  int t = threadIdx.x, c = blockIdx.x;
  int i = c * 1024 + t;
  int v = (i < NN) ? hist[i] : 0;
  sm[t] = v;
  for (int off = 1; off < 1024; off <<= 1) {
    __syncthreads();
    int a = (t >= off) ? sm[t - off] : 0;
    __syncthreads();
    sm[t] += a;
  }
  if (i < NN) inc[i] = sm[t];
  if (t == 1023) part[c] = sm[1023];
}

__global__ void k_scan_b(const int* __restrict__ part, int* __restrict__ offs) {
  int t = threadIdx.x;
  if (t >= 128) return;
  int run = 0;
  for (int c = 0; c < NCH; c++)
    if (c < t) run += part[c];
  if (t < NCH) offs[t] = run;
}

__global__ void k_scan_c(const int* __restrict__ hist, const int* __restrict__ inc,
                         const int* __restrict__ offs, int* __restrict__ rp,
                         int* __restrict__ cur) {
  int t = threadIdx.x, c = blockIdx.x;
  int i = c * 1024 + t;
  if (i < NN) {
    int r = inc[i] - hist[i] + offs[c];
    rp[i] = r;
    cur[i] = r;
  }
  if (i == 0) rp[NN] = ET;
}

__global__ void k_scatter(const int* __restrict__ edge, int* __restrict__ cur,
                          int* __restrict__ ssrc) {
  int e = blockIdx.x * 256 + threadIdx.x;
  if (e >= ET) return;
  int s, d;
  if (e < EE) { s = edge[e]; d = edge[EE + e]; } else { s = e - EE; d = s; }
  int pos = atomicAdd(&cur[d], 1);
  ssrc[pos] = s;
}

// ---------------- layer-1 aggregation (fp16 gathers, 8 edges/instr) ---------
__global__ __launch_bounds__(256) void k_aggB1(
    const __half* __restrict__ h1h, const __half* __restrict__ as1h,
    const float* __restrict__ ad1, const float* __restrict__ b1,
    const int* __restrict__ rp, const int* __restrict__ ssrc,
    const float* __restrict__ wsd2,
    __half* __restrict__ heluh, __half* __restrict__ as2h, float* __restrict__ ad2) {
  __shared__ float lds_p[4][512];
  __shared__ int   lds_s[4][64];
  __shared__ float lds_v[4][64];
  const int lane = threadIdx.x & 63;
  const int wv = threadIdx.x >> 6;
  const int d = blockIdx.x * 4 + wv;
  if (d >= NN) return;
  const int eg = lane >> 3;        // edge subgroup 0..7
  const int fl = lane & 7;         // 8-feature slice == head (phase B)
  float4 a0 = ((const float4*)ad1)[d * 2];
  float4 a1 = ((const float4*)ad1)[d * 2 + 1];
  const float adv[8] = {a0.x, a0.y, a0.z, a0.w, a1.x, a1.y, a1.z, a1.w};
  const int r0 = rp[d], r1 = rp[d + 1];
  float acc[8];
#pragma unroll
  for (int k = 0; k < 8; k++) acc[k] = 0.f;
  float lsum = 0.f;
  for (int base = r0; base < r1; base += 64) {
    int idx = base + lane;
    float p[8];
    int s = 0;
    if (idx < r1) {
      s = ssrc[idx];
      float4 raw = *((const float4*)&as1h[s * 8]);
      float ev[8];
      unpack8(raw, ev);
#pragma unroll
      for (int h = 0; h < 8; h++) {
        float e = ev[h] + adv[h];
        e = e > 0.f ? e : NEG * e;
        p[h] = __expf(e);
      }
    } else {
#pragma unroll
      for (int h = 0; h < 8; h++) p[h] = 0.f;
    }
    lds_s[wv][lane] = s;
    *((float4*)&lds_p[wv][lane * 8]) = make_float4(p[0], p[1], p[2], p[3]);
    *((float4*)&lds_p[wv][lane * 8 + 4]) = make_float4(p[4], p[5], p[6], p[7]);
    int nc = (min(64, r1 - base) + 7) >> 3;
#pragma unroll 2
    for (int j = 0; j < nc; j++) {
      int e = j * 8 + eg;
      int sj = lds_s[wv][e];
      float w = lds_p[wv][e * 8 + fl];
      float4 raw = *((const float4*)&h1h[(size_t)sj * 64 + fl * 8]);
      float g[8];
      unpack8(raw, g);
      lsum += w;
#pragma unroll
      for (int k = 0; k < 8; k++) acc[k] += w * g[k];
    }
  }
  // reduce across 8 edge subgroups (lane bits 3,4,5)
#pragma unroll
  for (int off = 8; off <= 32; off <<= 1) {
#pragma unroll
    for (int k = 0; k < 8; k++) acc[k] += __shfl_xor(acc[k], off, 64);
    lsum += __shfl_xor(lsum, off, 64);
  }
  if (lane < 8) {
#pragma unroll
    for (int k = 0; k < 8; k++) lds_v[wv][lane * 8 + k] = acc[k];
    lds_p[wv][lane] = lsum;   // l[head=lane]
  }
  float accs = lds_v[wv][lane];
  float lv = lds_p[wv][lane >> 3];
  float val = accs / lv + b1[lane];
  val = val > 0.f ? val : __expf(val) - 1.f;  // ELU
  heluh[(size_t)d * 64 + lane] = __float2half(val);
  // layer-2 logits: 4 groups of 16 features x 16 outputs (8 src + 8 dst)
  lds_v[wv][lane] = val;
  int g = lane >> 4, j = lane & 15;
  float dot = 0.f;
#pragma unroll
  for (int f = 0; f < 16; f++) dot += lds_v[wv][g * 16 + f] * wsd2[(g * 16 + f) * 16 + j];
  dot += __shfl_xor(dot, 16, 64);
  dot += __shfl_xor(dot, 32, 64);
  if (lane < 16) {
    if (j < 8) as2h[d * 8 + j] = __float2half(dot);
    else       ad2[d * 8 + (j & 7)] = dot;
  }
}

// ---------------- layer-2 aggregation in 64-dim space (fp16, deferred matmul) --
__global__ __launch_bounds__(256) void k_aggB2(
    const __half* __restrict__ heluh, const __half* __restrict__ as2h,
    const float* __restrict__ ad2, const int* __restrict__ rp,
    const int* __restrict__ ssrc, __half* __restrict__ aggh) {
  __shared__ float lds_p[4][512];
  __shared__ int   lds_s[4][64];
  const int lane = threadIdx.x & 63;
  const int wv = threadIdx.x >> 6;
  const int d = blockIdx.x * 4 + wv;
  if (d >= NN) return;
  const int eg = lane >> 4;        // edge subgroup 0..3
  const int fl = lane & 15;        // 4-feature slice
  float4 a0 = ((const float4*)ad2)[d * 2];
  float4 a1 = ((const float4*)ad2)[d * 2 + 1];
  const float adv[8] = {a0.x, a0.y, a0.z, a0.w, a1.x, a1.y, a1.z, a1.w};
  const int r0 = rp[d], r1 = rp[d + 1];
  float l8[8];
  float acc[8][4];
#pragma unroll
  for (int h = 0; h < 8; h++) {
    l8[h] = 0.f;
#pragma unroll
    for (int k = 0; k < 4; k++) acc[h][k] = 0.f;
  }
  for (int base = r0; base < r1; base += 64) {
    int idx = base + lane;
    float p[8];
    int s = 0;
    if (idx < r1) {
      s = ssrc[idx];
      float4 raw = *((const float4*)&as2h[s * 8]);
      float ev[8];
      unpack8(raw, ev);
#pragma unroll
      for (int h = 0; h < 8; h++) {
        float e = ev[h] + adv[h];
        e = e > 0.f ? e : NEG * e;
        p[h] = __expf(e);
      }
    } else {
#pragma unroll
      for (int h = 0; h < 8; h++) p[h] = 0.f;
    }
    lds_s[wv][lane] = s;
    *((float4*)&lds_p[wv][lane * 8]) = make_float4(p[0], p[1], p[2], p[3]);
    *((float4*)&lds_p[wv][lane * 8 + 4]) = make_float4(p[4], p[5], p[6], p[7]);
    int nc = (min(64, r1 - base) + 3) >> 2;
#pragma unroll 2
    for (int j = 0; j < nc; j++) {
      int e = j * 4 + eg;
      int sj = lds_s[wv][e];
      float2 raw = *((const float2*)&heluh[(size_t)sj * 64 + fl * 4]);
      __half2* hp = (__half2*)&raw;
      float2 ga = __half22float2(hp[0]);
      float2 gb = __half22float2(hp[1]);
      float g[4] = {ga.x, ga.y, gb.x, gb.y};
      float4 w0 = *((const float4*)&lds_p[wv][e * 8]);
      float4 w1 = *((const float4*)&lds_p[wv][e * 8 + 4]);
      float w[8] = {w0.x, w0.y, w0.z, w0.w, w1.x, w1.y, w1.z, w1.w};
#pragma unroll
      for (int h = 0; h < 8; h++) {
        l8[h] += w[h];
#pragma unroll
        for (int k = 0; k < 4; k++) acc[h][k] += w[h] * g[k];
      }
    }
  }
  // reduce across 4 edge subgroups (lane bits 4,5)
#pragma unroll
  for (int off = 16; off <= 32; off <<= 1) {
#pragma unroll
    for (int h = 0; h < 8; h++) {
      l8[h] += __shfl_xor(l8[h], off, 64);
#pragma unroll
      for (int k = 0; k < 4; k++) acc[h][k] += __shfl_xor(acc[h][k], off, 64);
    }
  }
  if (lane < 16) {
#pragma unroll
    for (int h = 0; h < 8; h++) {
      float rl = 1.0f / l8[h];
      union { __half2 h2[2]; float2 f2; } u;
      u.h2[0] = __floats2half2_rn(acc[h][0] * rl, acc[h][1] * rl);
      u.h2[1] = __floats2half2_rn(acc[h][2] * rl, acc[h][3] * rl);
      *((float2*)&aggh[(size_t)d * 512 + h * 64 + fl * 4]) = u.f2;
    }
  }
}

// ---------------- GEMM2 via MFMA: out = (1/8)*aggh[N,512] @ W2t^T + b2 -------
// A fragment: A[m=lane&15][k=(lane>>4)*8+j] (16B contiguous from aggh row).
// B fragment: B[n=lane&15][k=(lane>>4)*8+j] (16B contiguous from W2t row; 64KB, L1-hot).
// C/D: col=lane&15, row=(lane>>4)*4+reg. Wave: 16-row strip x 4 col-tiles.
__global__ __launch_bounds__(256) void k_gemm2m(const __half* __restrict__ aggh,
                                                const _Float16* __restrict__ W2t,
                                                const float* __restrict__ b2,
                                                float* __restrict__ out) {
  const int lane = threadIdx.x & 63;
  const int wv = threadIdx.x >> 6;
  const int m16 = lane & 15;
  const int q = lane >> 4;
  const int row = blockIdx.x * 64 + wv * 16 + m16;
  const bool rok = row < NN;
  const _Float16* arow = (const _Float16*)aggh + (size_t)row * 512 + q * 8;
  half8_t zero8;
#pragma unroll
  for (int i = 0; i < 8; i++) zero8[i] = (_Float16)0.f;
  f32x4 c0 = {0.f, 0.f, 0.f, 0.f}, c1 = c0, c2 = c0, c3 = c0;
#pragma unroll
  for (int k0 = 0; k0 < 512; k0 += 32) {
    half8_t a = rok ? *((const half8_t*)(arow + k0)) : zero8;
    half8_t b0 = *((const half8_t*)(W2t + (size_t)(0 * 16 + m16) * 512 + k0 + q * 8));
    half8_t b1 = *((const half8_t*)(W2t + (size_t)(1 * 16 + m16) * 512 + k0 + q * 8));
    half8_t b2f = *((const half8_t*)(W2t + (size_t)(2 * 16 + m16) * 512 + k0 + q * 8));
    half8_t b3 = *((const half8_t*)(W2t + (size_t)(3 * 16 + m16) * 512 + k0 + q * 8));
    c0 = __builtin_amdgcn_mfma_f32_16x16x32_f16(a, b0, c0, 0, 0, 0);
    c1 = __builtin_amdgcn_mfma_f32_16x16x32_f16(a, b1, c1, 0, 0, 0);
    c2 = __builtin_amdgcn_mfma_f32_16x16x32_f16(a, b2f, c2, 0, 0, 0);
    c3 = __builtin_amdgcn_mfma_f32_16x16x32_f16(a, b3, c3, 0, 0, 0);
  }
  float bias0 = b2[0 * 16 + m16];
  float bias1 = b2[1 * 16 + m16];
  float bias2 = b2[2 * 16 + m16];
  float bias3 = b2[3 * 16 + m16];
#pragma unroll
  for (int r = 0; r < 4; r++) {
    int orow = blockIdx.x * 64 + wv * 16 + q * 4 + r;
    if (orow >= NN) continue;
    float* op = out + (size_t)orow * 64;
    op[0 * 16 + m16] = 0.125f * c0[r] + bias0;
    op[1 * 16 + m16] = 0.125f * c1[r] + bias1;
    op[2 * 16 + m16] = 0.125f * c2[r] + bias2;
    op[3 * 16 + m16] = 0.125f * c3[r] + bias3;
  }
}

extern "C" void kernel_launch(void* const* d_in, const int* in_sizes, int n_in,
                              void* d_out, int out_size, void* d_ws, size_t ws_size,
                              hipStream_t stream) {
  const float* x      = (const float*)d_in[0];
  const float* W1     = (const float*)d_in[1];
  const float* a_src1 = (const float*)d_in[2];
  const float* a_dst1 = (const float*)d_in[3];
  const float* b1     = (const float*)d_in[4];
  const float* W2     = (const float*)d_in[5];
  const float* a_src2 = (const float*)d_in[6];
  const float* a_dst2 = (const float*)d_in[7];
  const float* b2     = (const float*)d_in[8];
  const int*   edge   = (const int*)d_in[9];

  char* ws = (char*)d_ws;
  __half* h1h   = (__half*)(ws + OFF_H1H);
  __half* heluh = (__half*)(ws + OFF_HELU);
  __half* as1h  = (__half*)(ws + OFF_AS1H);
  float*  ad1   = (float*)(ws + OFF_AD1);
  __half* as2h  = (__half*)(ws + OFF_AS2H);
  float*  ad2   = (float*)(ws + OFF_AD2);
  float*  wsd2  = (float*)(ws + OFF_WSD2);
  _Float16* W2t = (_Float16*)(ws + OFF_W2T);
  int* hist   = (int*)(ws + OFF_HIST);
  int* inc    = (int*)(ws + OFF_INC);
  int* part   = (int*)(ws + OFF_PART);
  int* offs   = (int*)(ws + OFF_OFFS);
  int* rp     = (int*)(ws + OFF_RP);
  int* cur    = (int*)(ws + OFF_CUR);
  int* ssrc   = (int*)(ws + OFF_SRC);
  __half* aggh = (__half*)(ws + OFF_AGGH);
  float* out  = (float*)d_out;

  hipMemsetAsync(hist, 0, (size_t)NN * 4, stream);

  k_gemm1<<<(NN + 127) / 128, 128, 0, stream>>>(x, W1, a_src1, a_dst1, h1h, as1h, ad1);
  k_w2proj<<<1, 1024, 0, stream>>>(W2, a_src2, a_dst2, wsd2);
  k_w2t<<<128, 256, 0, stream>>>(W2, W2t);
  k_hist<<<(ET + 255) / 256, 256, 0, stream>>>(edge, hist);
  k_scan_a<<<NCH, 1024, 0, stream>>>(hist, inc, part);
  k_scan_b<<<1, 128, 0, stream>>>(part, offs);
  k_scan_c<<<NCH, 1024, 0, stream>>>(hist, inc, offs, rp, cur);
  k_scatter<<<(ET + 255) / 256, 256, 0, stream>>>(edge, cur, ssrc);
  k_aggB1<<<(NN + 3) / 4, 256, 0, stream>>>(h1h, as1h, ad1, b1, rp, ssrc, wsd2, heluh, as2h, ad2);
  k_aggB2<<<(NN + 3) / 4, 256, 0, stream>>>(heluh, as2h, ad2, rp, ssrc, aggh);
  k_gemm2m<<<(NN + 63) / 64, 256, 0, stream>>>(aggh, W2t, b2, out);
}

// Round 7
// 626.147 us; speedup vs baseline: 2.2935x; 1.1639x over previous
//
#include <hip/hip_runtime.h>
#include <hip/hip_fp16.h>
#include <math.h>

#define NN 100000
#define EE 1600000
#define ET 1700000   // EE + NN self loops
#define NEG 0.2f
#define NCH 98       // ceil(NN/1024)
#define PCH 8192     // edges per partition block
#define NPB 208      // ceil(ET/PCH)

typedef _Float16 half8_t __attribute__((ext_vector_type(8)));
typedef float f32x4 __attribute__((ext_vector_type(4)));

// ---------------- ws layout (bytes) ----------------
static constexpr size_t alignup(size_t x) { return (x + 255) & ~(size_t)255; }
static constexpr size_t OFF_H1H  = 0;                                    // N*64 fp16
static constexpr size_t OFF_HELU = alignup(OFF_H1H  + (size_t)NN*64*2);  // N*64 fp16
static constexpr size_t OFF_AS1H = alignup(OFF_HELU + (size_t)NN*64*2);  // N*8 fp16
static constexpr size_t OFF_AD1  = alignup(OFF_AS1H + (size_t)NN*8*2);   // N*8 f32
static constexpr size_t OFF_AS2H = alignup(OFF_AD1  + (size_t)NN*8*4);   // N*8 fp16
static constexpr size_t OFF_AD2  = alignup(OFF_AS2H + (size_t)NN*8*2);   // N*8 f32
static constexpr size_t OFF_WSD2 = alignup(OFF_AD2  + (size_t)NN*8*4);   // 64*16 f32
static constexpr size_t OFF_W2T  = alignup(OFF_WSD2 + 64*16*4);          // 64*512 fp16
static constexpr size_t OFF_W1T  = alignup(OFF_W2T  + 64*512*2);         // 64*256 fp16
static constexpr size_t OFF_HIST = alignup(OFF_W1T  + 64*256*2);         // N int
static constexpr size_t OFF_INC  = alignup(OFF_HIST + (size_t)NN*4);
static constexpr size_t OFF_PART = alignup(OFF_INC  + (size_t)NN*4);
static constexpr size_t OFF_OFFS = alignup(OFF_PART + 128*4);
static constexpr size_t OFF_RP   = alignup(OFF_OFFS + 128*4);
static constexpr size_t OFF_CUR  = alignup(OFF_RP   + (size_t)(NN+1)*4);
static constexpr size_t OFF_SRC  = alignup(OFF_CUR  + (size_t)NN*4);     // ET int
static constexpr size_t OFF_BCUR = alignup(OFF_SRC  + (size_t)ET*4);     // 128 int
static constexpr size_t OFF_BKT  = alignup(OFF_BCUR + 128*4);            // ET u64
static constexpr size_t OFF_AGGH = alignup(OFF_BKT  + (size_t)ET*8);     // N*512 fp16

__device__ inline void unpack8(float4 raw, float* g) {
  __half2* hp = (__half2*)&raw;
  float2 a = __half22float2(hp[0]); g[0] = a.x; g[1] = a.y;
  float2 b = __half22float2(hp[1]); g[2] = b.x; g[3] = b.y;
  float2 c = __half22float2(hp[2]); g[4] = c.x; g[5] = c.y;
  float2 d = __half22float2(hp[3]); g[6] = d.x; g[7] = d.y;
}

// ---------------- W1t[f][k] = fp16(W1[k][f]) ----------------
__global__ void k_w1t(const float* __restrict__ W1, _Float16* __restrict__ W1t) {
  int t = blockIdx.x * 256 + threadIdx.x;  // 16384 = 64*256
  if (t >= 64 * 256) return;
  int f = t >> 8, k = t & 255;
  W1t[t] = (_Float16)W1[k * 64 + f];
}

// ---------------- GEMM1 via MFMA: h1h = fp16(x[N,256] @ W1t^T) --------------
// A: lane reads 8 consecutive fp32 of its row, converts to fp16 fragment.
// B: W1t rows (32KB, L1-hot). C/D: col=lane&15, row=(lane>>4)*4+reg.
__global__ __launch_bounds__(256) void k_gemm1m(const float* __restrict__ x,
                                                const _Float16* __restrict__ W1t,
                                                __half* __restrict__ h1h) {
  const int lane = threadIdx.x & 63;
  const int wv = threadIdx.x >> 6;
  const int m16 = lane & 15;
  const int q = lane >> 4;
  const int row = blockIdx.x * 64 + wv * 16 + m16;
  const bool rok = row < NN;
  const float* xr = x + (size_t)row * 256 + q * 8;
  f32x4 c0 = {0.f, 0.f, 0.f, 0.f}, c1 = c0, c2 = c0, c3 = c0;
#pragma unroll
  for (int k0 = 0; k0 < 256; k0 += 32) {
    half8_t a;
    if (rok) {
      float4 xa = ((const float4*)(xr + k0))[0];
      float4 xb = ((const float4*)(xr + k0))[1];
      a[0] = (_Float16)xa.x; a[1] = (_Float16)xa.y;
      a[2] = (_Float16)xa.z; a[3] = (_Float16)xa.w;
      a[4] = (_Float16)xb.x; a[5] = (_Float16)xb.y;
      a[6] = (_Float16)xb.z; a[7] = (_Float16)xb.w;
    } else {
#pragma unroll
      for (int i = 0; i < 8; i++) a[i] = (_Float16)0.f;
    }
    half8_t b0 = *((const half8_t*)(W1t + (size_t)(0 * 16 + m16) * 256 + k0 + q * 8));
    half8_t b1 = *((const half8_t*)(W1t + (size_t)(1 * 16 + m16) * 256 + k0 + q * 8));
    half8_t b2 = *((const half8_t*)(W1t + (size_t)(2 * 16 + m16) * 256 + k0 + q * 8));
    half8_t b3 = *((const half8_t*)(W1t + (size_t)(3 * 16 + m16) * 256 + k0 + q * 8));
    c0 = __builtin_amdgcn_mfma_f32_16x16x32_f16(a, b0, c0, 0, 0, 0);
    c1 = __builtin_amdgcn_mfma_f32_16x16x32_f16(a, b1, c1, 0, 0, 0);
    c2 = __builtin_amdgcn_mfma_f32_16x16x32_f16(a, b2, c2, 0, 0, 0);
    c3 = __builtin_amdgcn_mfma_f32_16x16x32_f16(a, b3, c3, 0, 0, 0);
  }
#pragma unroll
  for (int r = 0; r < 4; r++) {
    int orow = blockIdx.x * 64 + wv * 16 + q * 4 + r;
    if (orow >= NN) continue;
    __half* op = h1h + (size_t)orow * 64;
    op[0 * 16 + m16] = __float2half(c0[r]);
    op[1 * 16 + m16] = __float2half(c1[r]);
    op[2 * 16 + m16] = __float2half(c2[r]);
    op[3 * 16 + m16] = __float2half(c3[r]);
  }
}

// ---------------- attention logits from h1h ----------------
__global__ void k_alpha1h(const __half* __restrict__ h1h, const float* __restrict__ a_src1,
                          const float* __restrict__ a_dst1, __half* __restrict__ as1h,
                          float* __restrict__ ad1) {
  int g = blockIdx.x * 256 + threadIdx.x;
  if (g >= NN * 8) return;
  int n = g >> 3, h = g & 7;
  float4 raw = *((const float4*)&h1h[(size_t)n * 64 + h * 8]);
  float v[8];
  unpack8(raw, v);
  float s = 0.f, d = 0.f;
#pragma unroll
  for (int f = 0; f < 8; f++) {
    s += v[f] * a_src1[h * 8 + f];
    d += v[f] * a_dst1[h * 8 + f];
  }
  as1h[g] = __float2half(s);
  ad1[g] = d;
}

// ---------------- wsd2[k*16+j]: j<8 -> W2-proj of a_src2, else a_dst2 --------
__global__ void k_w2proj(const float* __restrict__ W2, const float* __restrict__ a_src2,
                         const float* __restrict__ a_dst2, float* __restrict__ wsd2) {
  int t = threadIdx.x;  // 1024 threads: t = k*16+j
  int k = t >> 4, j = t & 15, h = j & 7;
  const float* av = (j < 8) ? a_src2 : a_dst2;
  float s = 0.f;
  for (int f = 0; f < 64; f++) s += W2[k * 512 + h * 64 + f] * av[h * 64 + f];
  wsd2[t] = s;
}

// ---------------- W2t[f][h*64+kk] = fp16(W2[kk][h*64+f]) --------------------
__global__ void k_w2t(const float* __restrict__ W2, _Float16* __restrict__ W2t) {
  int t = blockIdx.x * 256 + threadIdx.x;  // 32768 = 64*512
  if (t >= 64 * 512) return;
  int f = t >> 9, k = t & 511;
  int h = k >> 6, kk = k & 63;
  W2t[t] = (_Float16)W2[kk * 512 + h * 64 + f];
}

// ---------------- counting sort by dst ----------------
__global__ void k_hist(const int* __restrict__ edge, int* __restrict__ hist) {
  int e = blockIdx.x * 256 + threadIdx.x;
  if (e >= ET) return;
  int d = (e < EE) ? edge[EE + e] : (e - EE);
  atomicAdd(&hist[d], 1);
}

__global__ void k_scan_a(const int* __restrict__ hist, int* __restrict__ inc,
                         int* __restrict__ part) {
  __shared__ int sm[1024];
  int t = threadIdx.x, c = blockIdx.x;
  int i = c * 1024 + t;
  int v = (i < NN) ? hist[i] : 0;
  sm[t] = v;
  for (int off = 1; off < 1024; off <<= 1) {
    __syncthreads();
    int a = (t >= off) ? sm[t - off] : 0;
    __syncthreads();
    sm[t] += a;
  }
  if (i < NN) inc[i] = sm[t];
  if (t == 1023) part[c] = sm[1023];
}

__global__ void k_scan_b(const int* __restrict__ part, int* __restrict__ offs) {
  int t = threadIdx.x;
  if (t >= 128) return;
  int run = 0;
  for (int c = 0; c < NCH; c++)
    if (c < t) run += part[c];
  if (t < NCH) offs[t] = run;
}

__global__ void k_scan_c(const int* __restrict__ hist, const int* __restrict__ inc,
                         const int* __restrict__ offs, int* __restrict__ rp,
                         int* __restrict__ cur) {
  int t = threadIdx.x, c = blockIdx.x;
  int i = c * 1024 + t;
  if (i < NN) {
    int r = inc[i] - hist[i] + offs[c];
    rp[i] = r;
    cur[i] = r;
  }
  if (i == 0) rp[NN] = ET;
}

// bucket cursors: bucket b covers dsts [b*1024,(b+1)*1024); base = rp[b*1024]
__global__ void k_bcur(const int* __restrict__ rp, int* __restrict__ bcur) {
  int t = threadIdx.x;
  if (t < 128) bcur[t] = rp[min(t * 1024, NN)];
}

// ---------------- pass A: partition edges into dst-buckets (packed u64) -----
__global__ __launch_bounds__(256) void k_part(const int* __restrict__ edge,
                                              int* __restrict__ bcur,
                                              unsigned long long* __restrict__ bkt) {
  __shared__ int lcnt[128];
  __shared__ int lbase[128];
  __shared__ int loff[128];
  const int t = threadIdx.x;
  const int e0 = blockIdx.x * PCH;
  if (t < 128) { lcnt[t] = 0; loff[t] = 0; }
  __syncthreads();
  for (int i = t; i < PCH; i += 256) {
    int e = e0 + i;
    if (e >= ET) break;
    int d = (e < EE) ? edge[EE + e] : (e - EE);
    atomicAdd(&lcnt[d >> 10], 1);
  }
  __syncthreads();
  if (t < 128 && lcnt[t] > 0) lbase[t] = atomicAdd(&bcur[t], lcnt[t]);
  __syncthreads();
  for (int i = t; i < PCH; i += 256) {
    int e = e0 + i;
    if (e >= ET) break;
    int s, d;
    if (e < EE) { s = edge[e]; d = edge[EE + e]; } else { s = e - EE; d = s; }
    int b = d >> 10;
    int off = atomicAdd(&loff[b], 1);
    bkt[(size_t)lbase[b] + off] = ((unsigned long long)d << 32) | (unsigned)s;
  }
}

// ---------------- pass B: finalize per-dst scatter (writes stay L2-local) ---
__global__ void k_scatfin(const unsigned long long* __restrict__ bkt,
                          int* __restrict__ cur, int* __restrict__ ssrc) {
  int e = blockIdx.x * 256 + threadIdx.x;
  if (e >= ET) return;
  unsigned long long v = bkt[e];
  int d = (int)(v >> 32);
  int s = (int)(v & 0xffffffffu);
  int pos = atomicAdd(&cur[d], 1);
  ssrc[pos] = s;
}

// ---------------- layer-1 aggregation (fp16 gathers, 8 edges/instr) ---------
__global__ __launch_bounds__(256) void k_aggB1(
    const __half* __restrict__ h1h, const __half* __restrict__ as1h,
    const float* __restrict__ ad1, const float* __restrict__ b1,
    const int* __restrict__ rp, const int* __restrict__ ssrc,
    const float* __restrict__ wsd2,
    __half* __restrict__ heluh, __half* __restrict__ as2h, float* __restrict__ ad2) {
  __shared__ float lds_p[4][512];
  __shared__ int   lds_s[4][64];
  __shared__ float lds_v[4][64];
  const int lane = threadIdx.x & 63;
  const int wv = threadIdx.x >> 6;
  const int d = blockIdx.x * 4 + wv;
  if (d >= NN) return;
  const int eg = lane >> 3;        // edge subgroup 0..7
  const int fl = lane & 7;         // 8-feature slice == head (phase B)
  float4 a0 = ((const float4*)ad1)[d * 2];
  float4 a1 = ((const float4*)ad1)[d * 2 + 1];
  const float adv[8] = {a0.x, a0.y, a0.z, a0.w, a1.x, a1.y, a1.z, a1.w};
  const int r0 = rp[d], r1 = rp[d + 1];
  float acc[8];
#pragma unroll
  for (int k = 0; k < 8; k++) acc[k] = 0.f;
  float lsum = 0.f;
  for (int base = r0; base < r1; base += 64) {
    int idx = base + lane;
    float p[8];
    int s = 0;
    if (idx < r1) {
      s = ssrc[idx];
      float4 raw = *((const float4*)&as1h[s * 8]);
      float ev[8];
      unpack8(raw, ev);
#pragma unroll
      for (int h = 0; h < 8; h++) {
        float e = ev[h] + adv[h];
        e = e > 0.f ? e : NEG * e;
        p[h] = __expf(e);
      }
    } else {
#pragma unroll
      for (int h = 0; h < 8; h++) p[h] = 0.f;
    }
    lds_s[wv][lane] = s;
    *((float4*)&lds_p[wv][lane * 8]) = make_float4(p[0], p[1], p[2], p[3]);
    *((float4*)&lds_p[wv][lane * 8 + 4]) = make_float4(p[4], p[5], p[6], p[7]);
    int nc = (min(64, r1 - base) + 7) >> 3;
#pragma unroll 2
    for (int j = 0; j < nc; j++) {
      int e = j * 8 + eg;
      int sj = lds_s[wv][e];
      float w = lds_p[wv][e * 8 + fl];
      float4 raw = *((const float4*)&h1h[(size_t)sj * 64 + fl * 8]);
      float g[8];
      unpack8(raw, g);
      lsum += w;
#pragma unroll
      for (int k = 0; k < 8; k++) acc[k] += w * g[k];
    }
  }
  // reduce across 8 edge subgroups (lane bits 3,4,5)
#pragma unroll
  for (int off = 8; off <= 32; off <<= 1) {
#pragma unroll
    for (int k = 0; k < 8; k++) acc[k] += __shfl_xor(acc[k], off, 64);
    lsum += __shfl_xor(lsum, off, 64);
  }
  if (lane < 8) {
#pragma unroll
    for (int k = 0; k < 8; k++) lds_v[wv][lane * 8 + k] = acc[k];
    lds_p[wv][lane] = lsum;   // l[head=lane]
  }
  float accs = lds_v[wv][lane];
  float lv = lds_p[wv][lane >> 3];
  float val = accs / lv + b1[lane];
  val = val > 0.f ? val : __expf(val) - 1.f;  // ELU
  heluh[(size_t)d * 64 + lane] = __float2half(val);
  // layer-2 logits: 4 groups of 16 features x 16 outputs (8 src + 8 dst)
  lds_v[wv][lane] = val;
  int g = lane >> 4, j = lane & 15;
  float dot = 0.f;
#pragma unroll
  for (int f = 0; f < 16; f++) dot += lds_v[wv][g * 16 + f] * wsd2[(g * 16 + f) * 16 + j];
  dot += __shfl_xor(dot, 16, 64);
  dot += __shfl_xor(dot, 32, 64);
  if (lane < 16) {
    if (j < 8) as2h[d * 8 + j] = __float2half(dot);
    else       ad2[d * 8 + (j & 7)] = dot;
  }
}

// ---------------- layer-2 aggregation in 64-dim space (fp16, deferred matmul) --
__global__ __launch_bounds__(256) void k_aggB2(
    const __half* __restrict__ heluh, const __half* __restrict__ as2h,
    const float* __restrict__ ad2, const int* __restrict__ rp,
    const int* __restrict__ ssrc, __half* __restrict__ aggh) {
  __shared__ float lds_p[4][512];
  __shared__ int   lds_s[4][64];
  const int lane = threadIdx.x & 63;
  const int wv = threadIdx.x >> 6;
  const int d = blockIdx.x * 4 + wv;
  if (d >= NN) return;
  const int eg = lane >> 4;        // edge subgroup 0..3
  const int fl = lane & 15;        // 4-feature slice
  float4 a0 = ((const float4*)ad2)[d * 2];
  float4 a1 = ((const float4*)ad2)[d * 2 + 1];
  const float adv[8] = {a0.x, a0.y, a0.z, a0.w, a1.x, a1.y, a1.z, a1.w};
  const int r0 = rp[d], r1 = rp[d + 1];
  float l8[8];
  float acc[8][4];
#pragma unroll
  for (int h = 0; h < 8; h++) {
    l8[h] = 0.f;
#pragma unroll
    for (int k = 0; k < 4; k++) acc[h][k] = 0.f;
  }
  for (int base = r0; base < r1; base += 64) {
    int idx = base + lane;
    float p[8];
    int s = 0;
    if (idx < r1) {
      s = ssrc[idx];
      float4 raw = *((const float4*)&as2h[s * 8]);
      float ev[8];
      unpack8(raw, ev);
#pragma unroll
      for (int h = 0; h < 8; h++) {
        float e = ev[h] + adv[h];
        e = e > 0.f ? e : NEG * e;
        p[h] = __expf(e);
      }
    } else {
#pragma unroll
      for (int h = 0; h < 8; h++) p[h] = 0.f;
    }
    lds_s[wv][lane] = s;
    *((float4*)&lds_p[wv][lane * 8]) = make_float4(p[0], p[1], p[2], p[3]);
    *((float4*)&lds_p[wv][lane * 8 + 4]) = make_float4(p[4], p[5], p[6], p[7]);
    int nc = (min(64, r1 - base) + 3) >> 2;
#pragma unroll 2
    for (int j = 0; j < nc; j++) {
      int e = j * 4 + eg;
      int sj = lds_s[wv][e];
      float2 raw = *((const float2*)&heluh[(size_t)sj * 64 + fl * 4]);
      __half2* hp = (__half2*)&raw;
      float2 ga = __half22float2(hp[0]);
      float2 gb = __half22float2(hp[1]);
      float g[4] = {ga.x, ga.y, gb.x, gb.y};
      float4 w0 = *((const float4*)&lds_p[wv][e * 8]);
      float4 w1 = *((const float4*)&lds_p[wv][e * 8 + 4]);
      float w[8] = {w0.x, w0.y, w0.z, w0.w, w1.x, w1.y, w1.z, w1.w};
#pragma unroll
      for (int h = 0; h < 8; h++) {
        l8[h] += w[h];
#pragma unroll
        for (int k = 0; k < 4; k++) acc[h][k] += w[h] * g[k];
      }
    }
  }
  // reduce across 4 edge subgroups (lane bits 4,5)
#pragma unroll
  for (int off = 16; off <= 32; off <<= 1) {
#pragma unroll
    for (int h = 0; h < 8; h++) {
      l8[h] += __shfl_xor(l8[h], off, 64);
#pragma unroll
      for (int k = 0; k < 4; k++) acc[h][k] += __shfl_xor(acc[h][k], off, 64);
    }
  }
  if (lane < 16) {
#pragma unroll
    for (int h = 0; h < 8; h++) {
      float rl = 1.0f / l8[h];
      union { __half2 h2[2]; float2 f2; } u;
      u.h2[0] = __floats2half2_rn(acc[h][0] * rl, acc[h][1] * rl);
      u.h2[1] = __floats2half2_rn(acc[h][2] * rl, acc[h][3] * rl);
      *((float2*)&aggh[(size_t)d * 512 + h * 64 + fl * 4]) = u.f2;
    }
  }
}

// ---------------- GEMM2 via MFMA: out = (1/8)*aggh[N,512] @ W2t^T + b2 -------
__global__ __launch_bounds__(256) void k_gemm2m(const __half* __restrict__ aggh,
                                                const _Float16* __restrict__ W2t,
                                                const float* __restrict__ b2,
                                                float* __restrict__ out) {
  const int lane = threadIdx.x & 63;
  const int wv = threadIdx.x >> 6;
  const int m16 = lane & 15;
  const int q = lane >> 4;
  const int row = blockIdx.x * 64 + wv * 16 + m16;
  const bool rok = row < NN;
  const _Float16* arow = (const _Float16*)aggh + (size_t)row * 512 + q * 8;
  half8_t zero8;
#pragma unroll
  for (int i = 0; i < 8; i++) zero8[i] = (_Float16)0.f;
  f32x4 c0 = {0.f, 0.f, 0.f, 0.f}, c1 = c0, c2 = c0, c3 = c0;
#pragma unroll
  for (int k0 = 0; k0 < 512; k0 += 32) {
    half8_t a = rok ? *((const half8_t*)(arow + k0)) : zero8;
    half8_t b0 = *((const half8_t*)(W2t + (size_t)(0 * 16 + m16) * 512 + k0 + q * 8));
    half8_t b1 = *((const half8_t*)(W2t + (size_t)(1 * 16 + m16) * 512 + k0 + q * 8));
    half8_t b2f = *((const half8_t*)(W2t + (size_t)(2 * 16 + m16) * 512 + k0 + q * 8));
    half8_t b3 = *((const half8_t*)(W2t + (size_t)(3 * 16 + m16) * 512 + k0 + q * 8));
    c0 = __builtin_amdgcn_mfma_f32_16x16x32_f16(a, b0, c0, 0, 0, 0);
    c1 = __builtin_amdgcn_mfma_f32_16x16x32_f16(a, b1, c1, 0, 0, 0);
    c2 = __builtin_amdgcn_mfma_f32_16x16x32_f16(a, b2f, c2, 0, 0, 0);
    c3 = __builtin_amdgcn_mfma_f32_16x16x32_f16(a, b3, c3, 0, 0, 0);
  }
  float bias0 = b2[0 * 16 + m16];
  float bias1 = b2[1 * 16 + m16];
  float bias2 = b2[2 * 16 + m16];
  float bias3 = b2[3 * 16 + m16];
#pragma unroll
  for (int r = 0; r < 4; r++) {
    int orow = blockIdx.x * 64 + wv * 16 + q * 4 + r;
    if (orow >= NN) continue;
    float* op = out + (size_t)orow * 64;
    op[0 * 16 + m16] = 0.125f * c0[r] + bias0;
    op[1 * 16 + m16] = 0.125f * c1[r] + bias1;
    op[2 * 16 + m16] = 0.125f * c2[r] + bias2;
    op[3 * 16 + m16] = 0.125f * c3[r] + bias3;
  }
}

extern "C" void kernel_launch(void* const* d_in, const int* in_sizes, int n_in,
                              void* d_out, int out_size, void* d_ws, size_t ws_size,
                              hipStream_t stream) {
  const float* x      = (const float*)d_in[0];
  const float* W1     = (const float*)d_in[1];
  const float* a_src1 = (const float*)d_in[2];
  const float* a_dst1 = (const float*)d_in[3];
  const float* b1     = (const float*)d_in[4];
  const float* W2     = (const float*)d_in[5];
  const float* a_src2 = (const float*)d_in[6];
  const float* a_dst2 = (const float*)d_in[7];
  const float* b2     = (const float*)d_in[8];
  const int*   edge   = (const int*)d_in[9];

  char* ws = (char*)d_ws;
  __half* h1h   = (__half*)(ws + OFF_H1H);
  __half* heluh = (__half*)(ws + OFF_HELU);
  __half* as1h  = (__half*)(ws + OFF_AS1H);
  float*  ad1   = (float*)(ws + OFF_AD1);
  __half* as2h  = (__half*)(ws + OFF_AS2H);
  float*  ad2   = (float*)(ws + OFF_AD2);
  float*  wsd2  = (float*)(ws + OFF_WSD2);
  _Float16* W2t = (_Float16*)(ws + OFF_W2T);
  _Float16* W1t = (_Float16*)(ws + OFF_W1T);
  int* hist   = (int*)(ws + OFF_HIST);
  int* inc    = (int*)(ws + OFF_INC);
  int* part   = (int*)(ws + OFF_PART);
  int* offs   = (int*)(ws + OFF_OFFS);
  int* rp     = (int*)(ws + OFF_RP);
  int* cur    = (int*)(ws + OFF_CUR);
  int* ssrc   = (int*)(ws + OFF_SRC);
  int* bcur   = (int*)(ws + OFF_BCUR);
  unsigned long long* bkt = (unsigned long long*)(ws + OFF_BKT);
  __half* aggh = (__half*)(ws + OFF_AGGH);
  float* out  = (float*)d_out;

  hipMemsetAsync(hist, 0, (size_t)NN * 4, stream);

  k_w1t<<<64, 256, 0, stream>>>(W1, W1t);
  k_gemm1m<<<(NN + 63) / 64, 256, 0, stream>>>(x, W1t, h1h);
  k_alpha1h<<<(NN * 8 + 255) / 256, 256, 0, stream>>>(h1h, a_src1, a_dst1, as1h, ad1);
  k_w2proj<<<1, 1024, 0, stream>>>(W2, a_src2, a_dst2, wsd2);
  k_w2t<<<128, 256, 0, stream>>>(W2, W2t);
  k_hist<<<(ET + 255) / 256, 256, 0, stream>>>(edge, hist);
  k_scan_a<<<NCH, 1024, 0, stream>>>(hist, inc, part);
  k_scan_b<<<1, 128, 0, stream>>>(part, offs);
  k_scan_c<<<NCH, 1024, 0, stream>>>(hist, inc, offs, rp, cur);
  k_bcur<<<1, 128, 0, stream>>>(rp, bcur);
  k_part<<<NPB, 256, 0, stream>>>(edge, bcur, bkt);
  k_scatfin<<<(ET + 255) / 256, 256, 0, stream>>>(bkt, cur, ssrc);
  k_aggB1<<<(NN + 3) / 4, 256, 0, stream>>>(h1h, as1h, ad1, b1, rp, ssrc, wsd2, heluh, as2h, ad2);
  k_aggB2<<<(NN + 3) / 4, 256, 0, stream>>>(heluh, as2h, ad2, rp, ssrc, aggh);
  k_gemm2m<<<(NN + 63) / 64, 256, 0, stream>>>(aggh, W2t, b2, out);
}